// Round 2
// baseline (1789.518 us; speedup 1.0000x reference)
//
#include <hip/hip_runtime.h>
#include <math.h>

#define EPSF 1e-9f
#define INV_SQRT128 0.08838834764831845f

// ---------------- cross-ratio of x rows 0..3 (128 dims) ----------------
__global__ void k_cr_init(const float* __restrict__ x, double* __restrict__ crinit) {
    int l = threadIdx.x; // 64 threads
    const int pa[4] = {0, 1, 0, 1};
    const int pb[4] = {2, 3, 3, 2};
    double inner[4];
    for (int p = 0; p < 4; p++) {
        const float* a = x + pa[p] * 128;
        const float* b = x + pb[p] * 128;
        double s = (double)a[l] * (double)b[l];
        double t = (double)a[l + 64] * (double)b[l + 64];
        s += (l == 63) ? -t : t;  // index 127 is the time coord
        for (int off = 32; off; off >>= 1) s += __shfl_xor(s, off);
        inner[p] = s;
    }
    if (l == 0) {
        double num = inner[0] * inner[1];
        double den = inner[2] * inner[3];
        if (fabs(den) < 1e-9) den = 1e-9;
        crinit[0] = num / den;
    }
}

// ---------------- normalize x rows (127 spatial + 1 time) ----------------
__global__ void k_normx(const float* __restrict__ x, float* __restrict__ xp, int N) {
    int wid = (blockIdx.x * blockDim.x + threadIdx.x) >> 6;
    int l = threadIdx.x & 63;
    if (wid >= N) return;
    const float* r = x + (size_t)wid * 128;
    float a = r[l];
    float b = r[l + 64];
    float pp = a * a + ((l < 63) ? b * b : 0.f);
    for (int off = 32; off; off >>= 1) pp += __shfl_xor(pp, off);
    float nm = fmaxf(sqrtf(pp), EPSF);
    float* o = xp + (size_t)wid * 128;
    o[l] = a / nm;
    o[l + 64] = (l == 63) ? b : b / nm;
}

// ---------------- q/k/v projection + head-normalize ----------------
// Block = 256 threads = 4 waves, 1 wave/SIMD (launch_bounds(.,1) -> 512 VGPR cap
// so the 128-float weight row stays register-resident; (.,2) made the compiler
// rematerialize W loads every row -> 1.16 GB HBM traffic in round 1).
// Global wave slot -> (kind, head) combo; each combo covers rows strided.
__global__ void __launch_bounds__(256, 1)
k_qkv(const float* __restrict__ xp,
      const float* __restrict__ Wq, const float* __restrict__ bq,
      const float* __restrict__ Wk, const float* __restrict__ bk,
      const float* __restrict__ Wv, const float* __restrict__ bv,
      float* __restrict__ qn, float* __restrict__ kn, float* __restrict__ vb,
      int N) {
    int w = threadIdx.x >> 6;
    int lane = threadIdx.x & 63;
    int wslot = blockIdx.x * 4 + w;          // grid=768 blocks -> 3072 wave slots
    int combo = wslot % 6;                   // kind*2 + head
    int wrow0 = wslot / 6;
    int rstride = (gridDim.x * 4) / 6;       // 512
    int kind = combo >> 1;                   // 0=q,1=k,2=v
    int half = combo & 1;                    // head
    const float* W = (kind == 0) ? Wq : ((kind == 1) ? Wk : Wv);
    const float* bias = (kind == 0) ? bq : ((kind == 1) ? bk : bv);
    float* outp = (kind == 0) ? qn : ((kind == 1) ? kn : vb);
    int orow = half * 64 + lane;

    float4 wv[32];
    const float4* wp = (const float4*)(W + (size_t)orow * 128);
#pragma unroll
    for (int j = 0; j < 32; j++) wv[j] = wp[j];
    float br = bias[orow];

    for (int n = wrow0; n < N; n += rstride) {
        const float4* xr = (const float4*)(xp + (size_t)n * 128);
        float a0 = 0.f, a1 = 0.f, a2 = 0.f, a3 = 0.f;
#pragma unroll
        for (int j = 0; j < 32; j += 4) {
            float4 x0 = xr[j], x1 = xr[j + 1], x2 = xr[j + 2], x3 = xr[j + 3];
            a0 = fmaf(x0.x, wv[j].x, a0);
            a0 = fmaf(x0.y, wv[j].y, a0);
            a0 = fmaf(x0.z, wv[j].z, a0);
            a0 = fmaf(x0.w, wv[j].w, a0);
            a1 = fmaf(x1.x, wv[j + 1].x, a1);
            a1 = fmaf(x1.y, wv[j + 1].y, a1);
            a1 = fmaf(x1.z, wv[j + 1].z, a1);
            a1 = fmaf(x1.w, wv[j + 1].w, a1);
            a2 = fmaf(x2.x, wv[j + 2].x, a2);
            a2 = fmaf(x2.y, wv[j + 2].y, a2);
            a2 = fmaf(x2.z, wv[j + 2].z, a2);
            a2 = fmaf(x2.w, wv[j + 2].w, a2);
            a3 = fmaf(x3.x, wv[j + 3].x, a3);
            a3 = fmaf(x3.y, wv[j + 3].y, a3);
            a3 = fmaf(x3.z, wv[j + 3].z, a3);
            a3 = fmaf(x3.w, wv[j + 3].w, a3);
        }
        float acc = (a0 + a1) + (a2 + a3) + br;
        float val = acc;
        if (kind < 2) {
            float pp = (lane < 63) ? acc * acc : 0.f;
            for (int off = 32; off; off >>= 1) pp += __shfl_xor(pp, off);
            float nm = fmaxf(sqrtf(pp), EPSF);
            val = (lane < 63) ? (acc / nm) : acc;   // keep homogeneous coord
            if (kind == 0) {
                if (lane == 63) val = -val;          // fold uhg minus into q
                val *= INV_SQRT128;                  // fold 1/sqrt(IN_F) into q
            }
        }
        outp[(size_t)n * 128 + orow] = val;
    }
}

// ---------------- per-edge scores ----------------
// 32 lanes per edge: lanes 0-15 head0, 16-31 head1 (4 floats each).
__global__ void k_scores(const float* __restrict__ qn, const float* __restrict__ kn,
                         const int* __restrict__ ei, float* __restrict__ scores, int E) {
    int g = threadIdx.x >> 5;   // group in block (8)
    int l = threadIdx.x & 31;
    int head = l >> 4;
    int nGroups = (blockDim.x >> 5) * gridDim.x;
    for (int e = blockIdx.x * 8 + g; e < E; e += nGroups) {
        int r = ei[e];
        int c = ei[E + e];
        float4 q4 = ((const float4*)qn)[(size_t)r * 32 + l];
        float4 k4 = ((const float4*)kn)[(size_t)c * 32 + l];
        float p = q4.x * k4.x;
        p = fmaf(q4.y, k4.y, p);
        p = fmaf(q4.z, k4.z, p);
        p = fmaf(q4.w, k4.w, p);
        p += __shfl_xor(p, 1);
        p += __shfl_xor(p, 2);
        p += __shfl_xor(p, 4);
        p += __shfl_xor(p, 8);
        if ((l & 15) == 0) scores[(size_t)e * 2 + head] = p;
    }
}

// ---------------- global max over edges (per head) ----------------
__global__ void k_max(const float* __restrict__ scores, float* __restrict__ pmax, int E) {
    float m0 = -INFINITY, m1 = -INFINITY;
    int stride = blockDim.x * gridDim.x;
    for (int i = blockIdx.x * blockDim.x + threadIdx.x; i < E; i += stride) {
        float2 s = ((const float2*)scores)[i];
        m0 = fmaxf(m0, s.x);
        m1 = fmaxf(m1, s.y);
    }
    for (int off = 32; off; off >>= 1) {
        m0 = fmaxf(m0, __shfl_xor(m0, off));
        m1 = fmaxf(m1, __shfl_xor(m1, off));
    }
    __shared__ float sm[2][4];
    int w = threadIdx.x >> 6;
    if ((threadIdx.x & 63) == 0) { sm[0][w] = m0; sm[1][w] = m1; }
    __syncthreads();
    if (threadIdx.x == 0) {
        for (int i = 1; i < 4; i++) { m0 = fmaxf(m0, sm[0][i]); m1 = fmaxf(m1, sm[1][i]); }
        pmax[blockIdx.x * 2 + 0] = m0;
        pmax[blockIdx.x * 2 + 1] = m1;
    }
}

__global__ void k_max2(const float* __restrict__ pmax, float* __restrict__ mhead, int P) {
    float m0 = -INFINITY, m1 = -INFINITY;
    for (int i = threadIdx.x; i < P; i += blockDim.x) {
        m0 = fmaxf(m0, pmax[2 * i]);
        m1 = fmaxf(m1, pmax[2 * i + 1]);
    }
    for (int off = 32; off; off >>= 1) {
        m0 = fmaxf(m0, __shfl_xor(m0, off));
        m1 = fmaxf(m1, __shfl_xor(m1, off));
    }
    __shared__ float sm[2][4];
    int w = threadIdx.x >> 6;
    if ((threadIdx.x & 63) == 0) { sm[0][w] = m0; sm[1][w] = m1; }
    __syncthreads();
    if (threadIdx.x == 0) {
        for (int i = 1; i < 4; i++) { m0 = fmaxf(m0, sm[0][i]); m1 = fmaxf(m1, sm[1][i]); }
        mhead[0] = m0;
        mhead[1] = m1;
    }
}

// ---------------- global sum of exp (double accumulation) ----------------
__global__ void k_expsum(const float* __restrict__ scores, const float* __restrict__ mhead,
                         double* __restrict__ psum, int E) {
    double s0 = 0.0, s1 = 0.0;
    float m0 = mhead[0], m1 = mhead[1];
    int stride = blockDim.x * gridDim.x;
    for (int i = blockIdx.x * blockDim.x + threadIdx.x; i < E; i += stride) {
        float2 s = ((const float2*)scores)[i];
        s0 += exp((double)(s.x - m0));
        s1 += exp((double)(s.y - m1));
    }
    for (int off = 32; off; off >>= 1) {
        s0 += __shfl_xor(s0, off);
        s1 += __shfl_xor(s1, off);
    }
    __shared__ double sd[2][4];
    int w = threadIdx.x >> 6;
    if ((threadIdx.x & 63) == 0) { sd[0][w] = s0; sd[1][w] = s1; }
    __syncthreads();
    if (threadIdx.x == 0) {
        for (int i = 1; i < 4; i++) { s0 += sd[0][i]; s1 += sd[1][i]; }
        psum[blockIdx.x * 2 + 0] = s0;
        psum[blockIdx.x * 2 + 1] = s1;
    }
}

__global__ void k_sum2(const double* __restrict__ psum, float* __restrict__ sumf, int P) {
    double s0 = 0.0, s1 = 0.0;
    for (int i = threadIdx.x; i < P; i += blockDim.x) {
        s0 += psum[2 * i];
        s1 += psum[2 * i + 1];
    }
    for (int off = 32; off; off >>= 1) {
        s0 += __shfl_xor(s0, off);
        s1 += __shfl_xor(s1, off);
    }
    __shared__ double sd[2][4];
    int w = threadIdx.x >> 6;
    if ((threadIdx.x & 63) == 0) { sd[0][w] = s0; sd[1][w] = s1; }
    __syncthreads();
    if (threadIdx.x == 0) {
        for (int i = 1; i < 4; i++) { s0 += sd[0][i]; s1 += sd[1][i]; }
        sumf[0] = (float)s0;
        sumf[1] = (float)s1;
    }
}

// ---------------- CSR build ----------------
__global__ void k_hist(const int* __restrict__ ei, int* __restrict__ counts, int E) {
    int stride = blockDim.x * gridDim.x;
    for (int e = blockIdx.x * blockDim.x + threadIdx.x; e < E; e += stride)
        atomicAdd(&counts[ei[e]], 1);
}

__global__ void k_scan1(const int* __restrict__ counts, int* __restrict__ offs,
                        int* __restrict__ tsum, int N) {
    __shared__ int sd[256];
    int tile = blockIdx.x;
    int t = threadIdx.x;
    int i0 = tile * 1024 + t * 4;
    int v[4];
    int lsum = 0;
    for (int j = 0; j < 4; j++) {
        int idx = i0 + j;
        v[j] = (idx < N) ? counts[idx] : 0;
        lsum += v[j];
    }
    sd[t] = lsum;
    __syncthreads();
    for (int off = 1; off < 256; off <<= 1) {
        int val = sd[t];
        int add = (t >= off) ? sd[t - off] : 0;
        __syncthreads();
        sd[t] = val + add;
        __syncthreads();
    }
    int excl = (t == 0) ? 0 : sd[t - 1];
    if (t == 255) tsum[tile] = sd[255];
    int run = excl;
    for (int j = 0; j < 4; j++) {
        int idx = i0 + j;
        if (idx < N) offs[idx] = run;
        run += v[j];
    }
}

__global__ void k_scan2(int* __restrict__ tsum, int* __restrict__ offs, int T, int N) {
    if (threadIdx.x == 0) {
        int run = 0;
        for (int i = 0; i < T; i++) {
            int t = tsum[i];
            tsum[i] = run;
            run += t;
        }
        offs[N] = run;
    }
}

__global__ void k_scan3(int* __restrict__ offs, int* __restrict__ cursor,
                        const int* __restrict__ tsum, int N) {
    int i = blockIdx.x * blockDim.x + threadIdx.x;
    if (i < N) {
        int o = offs[i] + tsum[i >> 10];
        offs[i] = o;
        cursor[i] = o;
    }
}

__global__ void k_fill(const int* __restrict__ ei, int* __restrict__ cursor,
                       int* __restrict__ elist, int E) {
    int stride = blockDim.x * gridDim.x;
    for (int e = blockIdx.x * blockDim.x + threadIdx.x; e < E; e += stride) {
        int r = ei[e];
        int p = atomicAdd(&cursor[r], 1);
        elist[p] = e;
    }
}

// ---------------- aggregation: out_pre[n] = sum_e alpha*v[col] ----------------
__global__ void k_agg(const float* __restrict__ vb, const float* __restrict__ scores,
                      const int* __restrict__ ei, const int* __restrict__ offs,
                      const int* __restrict__ elist, const float* __restrict__ mhead,
                      const float* __restrict__ sumf, float* __restrict__ outp,
                      int N, int E) {
    int n = blockIdx.x * 8 + (threadIdx.x >> 5);
    if (n >= N) return;
    int l = threadIdx.x & 31;
    int head = l >> 4;
    float m = mhead[head];
    float sf = sumf[head];
    int s0 = offs[n], s1 = offs[n + 1];
    float4 acc = {0.f, 0.f, 0.f, 0.f};
    for (int i = s0; i < s1; i++) {
        int e = elist[i];
        int c = ei[E + e];
        float sc = scores[(size_t)e * 2 + head];
        float a = expf(sc - m) / sf;
        float4 v4 = ((const float4*)vb)[(size_t)c * 32 + l];
        acc.x = fmaf(v4.x, a, acc.x);
        acc.y = fmaf(v4.y, a, acc.y);
        acc.z = fmaf(v4.z, a, acc.z);
        acc.w = fmaf(v4.w, a, acc.w);
    }
    ((float4*)outp)[(size_t)n * 32 + l] = acc;
}

// ---------------- final GEMM: out = out_pre @ Wo.T + bo ----------------
// Same register-resident-weights treatment as k_qkv: launch_bounds(.,1).
__global__ void __launch_bounds__(256, 1)
k_out(const float* __restrict__ op, const float* __restrict__ Wo,
      const float* __restrict__ bo, float* __restrict__ out, int N) {
    int gw = (blockIdx.x * blockDim.x + threadIdx.x) >> 6;
    int nw = (gridDim.x * blockDim.x) >> 6;
    int o = threadIdx.x & 63;
    float4 wv[32];
    const float4* wp = (const float4*)(Wo + (size_t)o * 128);
#pragma unroll
    for (int j = 0; j < 32; j++) wv[j] = wp[j];
    float br = bo[o];
    for (int n = gw; n < N; n += nw) {
        const float4* r = (const float4*)(op + (size_t)n * 128);
        float a0 = 0.f, a1 = 0.f, a2 = 0.f, a3 = 0.f;
#pragma unroll
        for (int j = 0; j < 32; j += 4) {
            float4 x0 = r[j], x1 = r[j + 1], x2 = r[j + 2], x3 = r[j + 3];
            a0 = fmaf(x0.x, wv[j].x, a0);
            a0 = fmaf(x0.y, wv[j].y, a0);
            a0 = fmaf(x0.z, wv[j].z, a0);
            a0 = fmaf(x0.w, wv[j].w, a0);
            a1 = fmaf(x1.x, wv[j + 1].x, a1);
            a1 = fmaf(x1.y, wv[j + 1].y, a1);
            a1 = fmaf(x1.z, wv[j + 1].z, a1);
            a1 = fmaf(x1.w, wv[j + 1].w, a1);
            a2 = fmaf(x2.x, wv[j + 2].x, a2);
            a2 = fmaf(x2.y, wv[j + 2].y, a2);
            a2 = fmaf(x2.z, wv[j + 2].z, a2);
            a2 = fmaf(x2.w, wv[j + 2].w, a2);
            a3 = fmaf(x3.x, wv[j + 3].x, a3);
            a3 = fmaf(x3.y, wv[j + 3].y, a3);
            a3 = fmaf(x3.z, wv[j + 3].z, a3);
            a3 = fmaf(x3.w, wv[j + 3].w, a3);
        }
        out[(size_t)n * 64 + o] = (a0 + a1) + (a2 + a3) + br;
    }
}

// ---------------- cross-ratio restore ----------------
__global__ void k_crout(const float* __restrict__ out, const double* __restrict__ crinit,
                        float* __restrict__ scalef) {
    int l = threadIdx.x; // 64
    const int pa[4] = {0, 1, 0, 1};
    const int pb[4] = {2, 3, 3, 2};
    double inner[4];
    for (int p = 0; p < 4; p++) {
        const float* a = out + pa[p] * 64;
        const float* b = out + pb[p] * 64;
        double t = (double)a[l] * (double)b[l];
        if (l == 63) t = -t;
        for (int off = 32; off; off >>= 1) t += __shfl_xor(t, off);
        inner[p] = t;
    }
    if (l == 0) {
        double num = inner[0] * inner[1];
        double den = inner[2] * inner[3];
        if (fabs(den) < 1e-9) den = 1e-9;
        double crc = num / den;
        if (fabs(crc) < 1e-9) crc = 1e-9;
        double ratio = crinit[0] / crc;
        scalef[0] = (float)pow(fabs(ratio), 0.25);
    }
}

__global__ void k_scale(float* __restrict__ out, const float* __restrict__ scalef, int total4) {
    int i = blockIdx.x * blockDim.x + threadIdx.x;
    if (i >= total4) return;
    float s = scalef[0];
    float4 t = ((float4*)out)[i];
    t.x *= s; t.y *= s; t.z *= s; t.w *= s;
    ((float4*)out)[i] = t;
}

extern "C" void kernel_launch(void* const* d_in, const int* in_sizes, int n_in,
                              void* d_out, int out_size, void* d_ws, size_t ws_size,
                              hipStream_t stream) {
    const float* x  = (const float*)d_in[0];
    const int*   ei = (const int*)d_in[1];
    const float* Wq = (const float*)d_in[2];
    const float* bq = (const float*)d_in[3];
    const float* Wk = (const float*)d_in[4];
    const float* bk = (const float*)d_in[5];
    const float* Wv = (const float*)d_in[6];
    const float* bv = (const float*)d_in[7];
    const float* Wo = (const float*)d_in[8];
    const float* bo = (const float*)d_in[9];
    float* out = (float*)d_out;

    const int N = in_sizes[0] / 128;
    const int E = in_sizes[1] / 2;
    const size_t NR = (size_t)N * 128;

    float* qn = (float*)d_ws;       // N*128 ; later reused as out_pre
    float* kn = qn + NR;            // N*128
    float* vb = kn + NR;            // N*128
    float* xp = vb + NR;            // N*128 ; region reused after k_qkv:
    float* scores = xp;             //   E*2 floats
    int* counts = (int*)(scores + (size_t)E * 2);
    int* offs   = counts + N;       // N+1
    int* cursor = offs + N + 1;     // N
    int* elist  = cursor + N;       // E
    int* tsum   = elist + E;        // tiles

    double* crinit = (double*)(xp + NR);
    double* psum   = crinit + 1;            // 1024 doubles
    float* pmax    = (float*)(psum + 1024); // 1024 floats
    float* mhead   = pmax + 1024;           // 2
    float* sumf    = mhead + 2;             // 2
    float* scalef  = sumf + 2;              // 1

    float* out_pre = qn;  // reuse

    const int T = (N + 1023) / 1024;

    k_cr_init<<<1, 64, 0, stream>>>(x, crinit);
    k_normx<<<(N * 64 + 255) / 256, 256, 0, stream>>>(x, xp, N);
    k_qkv<<<768, 256, 0, stream>>>(xp, Wq, bq, Wk, bk, Wv, bv, qn, kn, vb, N);
    k_scores<<<2048, 256, 0, stream>>>(qn, kn, ei, scores, E);
    k_max<<<512, 256, 0, stream>>>(scores, pmax, E);
    k_max2<<<1, 256, 0, stream>>>(pmax, mhead, 512);
    k_expsum<<<512, 256, 0, stream>>>(scores, mhead, psum, E);
    k_sum2<<<1, 256, 0, stream>>>(psum, sumf, 512);
    hipMemsetAsync(counts, 0, (size_t)N * sizeof(int), stream);
    k_hist<<<1024, 256, 0, stream>>>(ei, counts, E);
    k_scan1<<<T, 256, 0, stream>>>(counts, offs, tsum, N);
    k_scan2<<<1, 64, 0, stream>>>(tsum, offs, T, N);
    k_scan3<<<(N + 255) / 256, 256, 0, stream>>>(offs, cursor, tsum, N);
    k_fill<<<1024, 256, 0, stream>>>(ei, cursor, elist, E);
    k_agg<<<(N + 7) / 8, 256, 0, stream>>>(vb, scores, ei, offs, elist, mhead, sumf, out_pre, N, E);
    k_out<<<512, 256, 0, stream>>>(out_pre, Wo, bo, out, N);
    k_crout<<<1, 64, 0, stream>>>(out, crinit, scalef);
    k_scale<<<(N * 16 + 255) / 256, 256, 0, stream>>>(out, scalef, N * 16);
}

// Round 3
// 1686.242 us; speedup vs baseline: 1.0612x; 1.0612x over previous
//
#include <hip/hip_runtime.h>
#include <math.h>

#define EPSF 1e-9f
#define INV_SQRT128 0.08838834764831845f

// ---------------- cross-ratio of x rows 0..3 (128 dims) ----------------
__global__ void k_cr_init(const float* __restrict__ x, double* __restrict__ crinit) {
    int l = threadIdx.x; // 64 threads
    const int pa[4] = {0, 1, 0, 1};
    const int pb[4] = {2, 3, 3, 2};
    double inner[4];
    for (int p = 0; p < 4; p++) {
        const float* a = x + pa[p] * 128;
        const float* b = x + pb[p] * 128;
        double s = (double)a[l] * (double)b[l];
        double t = (double)a[l + 64] * (double)b[l + 64];
        s += (l == 63) ? -t : t;  // index 127 is the time coord
        for (int off = 32; off; off >>= 1) s += __shfl_xor(s, off);
        inner[p] = s;
    }
    if (l == 0) {
        double num = inner[0] * inner[1];
        double den = inner[2] * inner[3];
        if (fabs(den) < 1e-9) den = 1e-9;
        crinit[0] = num / den;
    }
}

// ---------------- normalize x rows (127 spatial + 1 time) ----------------
__global__ void k_normx(const float* __restrict__ x, float* __restrict__ xp, int N) {
    int wid = (blockIdx.x * blockDim.x + threadIdx.x) >> 6;
    int l = threadIdx.x & 63;
    if (wid >= N) return;
    const float* r = x + (size_t)wid * 128;
    float a = r[l];
    float b = r[l + 64];
    float pp = a * a + ((l < 63) ? b * b : 0.f);
    for (int off = 32; off; off >>= 1) pp += __shfl_xor(pp, off);
    float nm = fmaxf(sqrtf(pp), EPSF);
    float* o = xp + (size_t)wid * 128;
    o[l] = a / nm;
    o[l + 64] = (l == 63) ? b : b / nm;
}

// ---------------- projection + head-normalize, one kernel per matrix ----------------
// KIND: 0=q (normalize + fold -sign on time coord + 1/sqrt(128)), 1=k (normalize), 2=v.
// W is passed DIRECTLY as __restrict__ (round-2 lesson: a runtime select between
// restrict pointers loses noalias provenance -> W loads can't hoist past the outp
// stores -> 32KB/wave re-read from L1 every row (VGPR=96, 1051us). Template makes
// the selection compile-time so the 128-float weight row stays in VGPRs.
// Block = 256 = 4 waves, launch_bounds(.,1) -> 512-VGPR budget.
template<int KIND>
__global__ void __launch_bounds__(256, 1)
k_proj(const float* __restrict__ xp, const float* __restrict__ W,
       const float* __restrict__ bias, float* __restrict__ outp, int N) {
    int w = threadIdx.x >> 6;
    int lane = threadIdx.x & 63;
    int ws = blockIdx.x * 4 + w;        // wave slot
    int half = ws & 1;                  // head
    int n0 = ws >> 1;
    int rstride = (gridDim.x * 4) >> 1;
    int orow = half * 64 + lane;

    float4 wv[32];
    const float4* wp = (const float4*)(W + (size_t)orow * 128);
#pragma unroll
    for (int j = 0; j < 32; j++) wv[j] = wp[j];
    float br = bias[orow];

    for (int n = n0; n < N; n += rstride) {
        const float4* xr = (const float4*)(xp + (size_t)n * 128);
        float a0 = 0.f, a1 = 0.f, a2 = 0.f, a3 = 0.f;
#pragma unroll
        for (int j = 0; j < 32; j += 4) {
            float4 x0 = xr[j], x1 = xr[j + 1], x2 = xr[j + 2], x3 = xr[j + 3];
            a0 = fmaf(x0.x, wv[j].x, a0);
            a0 = fmaf(x0.y, wv[j].y, a0);
            a0 = fmaf(x0.z, wv[j].z, a0);
            a0 = fmaf(x0.w, wv[j].w, a0);
            a1 = fmaf(x1.x, wv[j + 1].x, a1);
            a1 = fmaf(x1.y, wv[j + 1].y, a1);
            a1 = fmaf(x1.z, wv[j + 1].z, a1);
            a1 = fmaf(x1.w, wv[j + 1].w, a1);
            a2 = fmaf(x2.x, wv[j + 2].x, a2);
            a2 = fmaf(x2.y, wv[j + 2].y, a2);
            a2 = fmaf(x2.z, wv[j + 2].z, a2);
            a2 = fmaf(x2.w, wv[j + 2].w, a2);
            a3 = fmaf(x3.x, wv[j + 3].x, a3);
            a3 = fmaf(x3.y, wv[j + 3].y, a3);
            a3 = fmaf(x3.z, wv[j + 3].z, a3);
            a3 = fmaf(x3.w, wv[j + 3].w, a3);
        }
        float acc = (a0 + a1) + (a2 + a3) + br;
        float val = acc;
        if (KIND < 2) {
            float pp = (lane < 63) ? acc * acc : 0.f;
            for (int off = 32; off; off >>= 1) pp += __shfl_xor(pp, off);
            float nm = fmaxf(sqrtf(pp), EPSF);
            val = (lane < 63) ? (acc / nm) : acc;   // keep homogeneous coord
            if (KIND == 0) {
                if (lane == 63) val = -val;          // fold uhg minus into q
                val *= INV_SQRT128;                  // fold 1/sqrt(IN_F) into q
            }
        }
        outp[(size_t)n * 128 + orow] = val;
    }
}

// ---------------- per-edge scores ----------------
// 32 lanes per edge: lanes 0-15 head0, 16-31 head1 (4 floats each).
__global__ void k_scores(const float* __restrict__ qn, const float* __restrict__ kn,
                         const int* __restrict__ ei, float* __restrict__ scores, int E) {
    int g = threadIdx.x >> 5;   // group in block (8)
    int l = threadIdx.x & 31;
    int head = l >> 4;
    int nGroups = (blockDim.x >> 5) * gridDim.x;
    for (int e = blockIdx.x * 8 + g; e < E; e += nGroups) {
        int r = ei[e];
        int c = ei[E + e];
        float4 q4 = ((const float4*)qn)[(size_t)r * 32 + l];
        float4 k4 = ((const float4*)kn)[(size_t)c * 32 + l];
        float p = q4.x * k4.x;
        p = fmaf(q4.y, k4.y, p);
        p = fmaf(q4.z, k4.z, p);
        p = fmaf(q4.w, k4.w, p);
        p += __shfl_xor(p, 1);
        p += __shfl_xor(p, 2);
        p += __shfl_xor(p, 4);
        p += __shfl_xor(p, 8);
        if ((l & 15) == 0) scores[(size_t)e * 2 + head] = p;
    }
}

// ---------------- global max over edges (per head) ----------------
__global__ void k_max(const float* __restrict__ scores, float* __restrict__ pmax, int E) {
    float m0 = -INFINITY, m1 = -INFINITY;
    int stride = blockDim.x * gridDim.x;
    for (int i = blockIdx.x * blockDim.x + threadIdx.x; i < E; i += stride) {
        float2 s = ((const float2*)scores)[i];
        m0 = fmaxf(m0, s.x);
        m1 = fmaxf(m1, s.y);
    }
    for (int off = 32; off; off >>= 1) {
        m0 = fmaxf(m0, __shfl_xor(m0, off));
        m1 = fmaxf(m1, __shfl_xor(m1, off));
    }
    __shared__ float sm[2][4];
    int w = threadIdx.x >> 6;
    if ((threadIdx.x & 63) == 0) { sm[0][w] = m0; sm[1][w] = m1; }
    __syncthreads();
    if (threadIdx.x == 0) {
        for (int i = 1; i < 4; i++) { m0 = fmaxf(m0, sm[0][i]); m1 = fmaxf(m1, sm[1][i]); }
        pmax[blockIdx.x * 2 + 0] = m0;
        pmax[blockIdx.x * 2 + 1] = m1;
    }
}

__global__ void k_max2(const float* __restrict__ pmax, float* __restrict__ mhead, int P) {
    float m0 = -INFINITY, m1 = -INFINITY;
    for (int i = threadIdx.x; i < P; i += blockDim.x) {
        m0 = fmaxf(m0, pmax[2 * i]);
        m1 = fmaxf(m1, pmax[2 * i + 1]);
    }
    for (int off = 32; off; off >>= 1) {
        m0 = fmaxf(m0, __shfl_xor(m0, off));
        m1 = fmaxf(m1, __shfl_xor(m1, off));
    }
    __shared__ float sm[2][4];
    int w = threadIdx.x >> 6;
    if ((threadIdx.x & 63) == 0) { sm[0][w] = m0; sm[1][w] = m1; }
    __syncthreads();
    if (threadIdx.x == 0) {
        for (int i = 1; i < 4; i++) { m0 = fmaxf(m0, sm[0][i]); m1 = fmaxf(m1, sm[1][i]); }
        mhead[0] = m0;
        mhead[1] = m1;
    }
}

// ---------------- global sum of exp (double accumulation) ----------------
__global__ void k_expsum(const float* __restrict__ scores, const float* __restrict__ mhead,
                         double* __restrict__ psum, int E) {
    double s0 = 0.0, s1 = 0.0;
    float m0 = mhead[0], m1 = mhead[1];
    int stride = blockDim.x * gridDim.x;
    for (int i = blockIdx.x * blockDim.x + threadIdx.x; i < E; i += stride) {
        float2 s = ((const float2*)scores)[i];
        s0 += exp((double)(s.x - m0));
        s1 += exp((double)(s.y - m1));
    }
    for (int off = 32; off; off >>= 1) {
        s0 += __shfl_xor(s0, off);
        s1 += __shfl_xor(s1, off);
    }
    __shared__ double sd[2][4];
    int w = threadIdx.x >> 6;
    if ((threadIdx.x & 63) == 0) { sd[0][w] = s0; sd[1][w] = s1; }
    __syncthreads();
    if (threadIdx.x == 0) {
        for (int i = 1; i < 4; i++) { s0 += sd[0][i]; s1 += sd[1][i]; }
        psum[blockIdx.x * 2 + 0] = s0;
        psum[blockIdx.x * 2 + 1] = s1;
    }
}

__global__ void k_sum2(const double* __restrict__ psum, float* __restrict__ sumf, int P) {
    double s0 = 0.0, s1 = 0.0;
    for (int i = threadIdx.x; i < P; i += blockDim.x) {
        s0 += psum[2 * i];
        s1 += psum[2 * i + 1];
    }
    for (int off = 32; off; off >>= 1) {
        s0 += __shfl_xor(s0, off);
        s1 += __shfl_xor(s1, off);
    }
    __shared__ double sd[2][4];
    int w = threadIdx.x >> 6;
    if ((threadIdx.x & 63) == 0) { sd[0][w] = s0; sd[1][w] = s1; }
    __syncthreads();
    if (threadIdx.x == 0) {
        for (int i = 1; i < 4; i++) { s0 += sd[0][i]; s1 += sd[1][i]; }
        sumf[0] = (float)s0;
        sumf[1] = (float)s1;
    }
}

// ---------------- CSR build ----------------
__global__ void k_hist(const int* __restrict__ ei, int* __restrict__ counts, int E) {
    int stride = blockDim.x * gridDim.x;
    for (int e = blockIdx.x * blockDim.x + threadIdx.x; e < E; e += stride)
        atomicAdd(&counts[ei[e]], 1);
}

__global__ void k_scan1(const int* __restrict__ counts, int* __restrict__ offs,
                        int* __restrict__ tsum, int N) {
    __shared__ int sd[256];
    int tile = blockIdx.x;
    int t = threadIdx.x;
    int i0 = tile * 1024 + t * 4;
    int v[4];
    int lsum = 0;
    for (int j = 0; j < 4; j++) {
        int idx = i0 + j;
        v[j] = (idx < N) ? counts[idx] : 0;
        lsum += v[j];
    }
    sd[t] = lsum;
    __syncthreads();
    for (int off = 1; off < 256; off <<= 1) {
        int val = sd[t];
        int add = (t >= off) ? sd[t - off] : 0;
        __syncthreads();
        sd[t] = val + add;
        __syncthreads();
    }
    int excl = (t == 0) ? 0 : sd[t - 1];
    if (t == 255) tsum[tile] = sd[255];
    int run = excl;
    for (int j = 0; j < 4; j++) {
        int idx = i0 + j;
        if (idx < N) offs[idx] = run;
        run += v[j];
    }
}

__global__ void k_scan2(int* __restrict__ tsum, int* __restrict__ offs, int T, int N) {
    if (threadIdx.x == 0) {
        int run = 0;
        for (int i = 0; i < T; i++) {
            int t = tsum[i];
            tsum[i] = run;
            run += t;
        }
        offs[N] = run;
    }
}

__global__ void k_scan3(int* __restrict__ offs, int* __restrict__ cursor,
                        const int* __restrict__ tsum, int N) {
    int i = blockIdx.x * blockDim.x + threadIdx.x;
    if (i < N) {
        int o = offs[i] + tsum[i >> 10];
        offs[i] = o;
        cursor[i] = o;
    }
}

__global__ void k_fill(const int* __restrict__ ei, int* __restrict__ cursor,
                       int* __restrict__ elist, int E) {
    int stride = blockDim.x * gridDim.x;
    for (int e = blockIdx.x * blockDim.x + threadIdx.x; e < E; e += stride) {
        int r = ei[e];
        int p = atomicAdd(&cursor[r], 1);
        elist[p] = e;
    }
}

// ---------------- aggregation: out_pre[n] = sum_e alpha*v[col] ----------------
__global__ void k_agg(const float* __restrict__ vb, const float* __restrict__ scores,
                      const int* __restrict__ ei, const int* __restrict__ offs,
                      const int* __restrict__ elist, const float* __restrict__ mhead,
                      const float* __restrict__ sumf, float* __restrict__ outp,
                      int N, int E) {
    int n = blockIdx.x * 8 + (threadIdx.x >> 5);
    if (n >= N) return;
    int l = threadIdx.x & 31;
    int head = l >> 4;
    float m = mhead[head];
    float sf = sumf[head];
    int s0 = offs[n], s1 = offs[n + 1];
    float4 acc = {0.f, 0.f, 0.f, 0.f};
    for (int i = s0; i < s1; i++) {
        int e = elist[i];
        int c = ei[E + e];
        float sc = scores[(size_t)e * 2 + head];
        float a = expf(sc - m) / sf;
        float4 v4 = ((const float4*)vb)[(size_t)c * 32 + l];
        acc.x = fmaf(v4.x, a, acc.x);
        acc.y = fmaf(v4.y, a, acc.y);
        acc.z = fmaf(v4.z, a, acc.z);
        acc.w = fmaf(v4.w, a, acc.w);
    }
    ((float4*)outp)[(size_t)n * 32 + l] = acc;
}

// ---------------- final GEMM: out = out_pre @ Wo.T + bo ----------------
__global__ void __launch_bounds__(256, 1)
k_out(const float* __restrict__ op, const float* __restrict__ Wo,
      const float* __restrict__ bo, float* __restrict__ out, int N) {
    int gw = (blockIdx.x * blockDim.x + threadIdx.x) >> 6;
    int nw = (gridDim.x * blockDim.x) >> 6;
    int o = threadIdx.x & 63;
    float4 wv[32];
    const float4* wp = (const float4*)(Wo + (size_t)o * 128);
#pragma unroll
    for (int j = 0; j < 32; j++) wv[j] = wp[j];
    float br = bo[o];
    for (int n = gw; n < N; n += nw) {
        const float4* r = (const float4*)(op + (size_t)n * 128);
        float a0 = 0.f, a1 = 0.f, a2 = 0.f, a3 = 0.f;
#pragma unroll
        for (int j = 0; j < 32; j += 4) {
            float4 x0 = r[j], x1 = r[j + 1], x2 = r[j + 2], x3 = r[j + 3];
            a0 = fmaf(x0.x, wv[j].x, a0);
            a0 = fmaf(x0.y, wv[j].y, a0);
            a0 = fmaf(x0.z, wv[j].z, a0);
            a0 = fmaf(x0.w, wv[j].w, a0);
            a1 = fmaf(x1.x, wv[j + 1].x, a1);
            a1 = fmaf(x1.y, wv[j + 1].y, a1);
            a1 = fmaf(x1.z, wv[j + 1].z, a1);
            a1 = fmaf(x1.w, wv[j + 1].w, a1);
            a2 = fmaf(x2.x, wv[j + 2].x, a2);
            a2 = fmaf(x2.y, wv[j + 2].y, a2);
            a2 = fmaf(x2.z, wv[j + 2].z, a2);
            a2 = fmaf(x2.w, wv[j + 2].w, a2);
            a3 = fmaf(x3.x, wv[j + 3].x, a3);
            a3 = fmaf(x3.y, wv[j + 3].y, a3);
            a3 = fmaf(x3.z, wv[j + 3].z, a3);
            a3 = fmaf(x3.w, wv[j + 3].w, a3);
        }
        out[(size_t)n * 64 + o] = (a0 + a1) + (a2 + a3) + br;
    }
}

// ---------------- cross-ratio restore ----------------
__global__ void k_crout(const float* __restrict__ out, const double* __restrict__ crinit,
                        float* __restrict__ scalef) {
    int l = threadIdx.x; // 64
    const int pa[4] = {0, 1, 0, 1};
    const int pb[4] = {2, 3, 3, 2};
    double inner[4];
    for (int p = 0; p < 4; p++) {
        const float* a = out + pa[p] * 64;
        const float* b = out + pb[p] * 64;
        double t = (double)a[l] * (double)b[l];
        if (l == 63) t = -t;
        for (int off = 32; off; off >>= 1) t += __shfl_xor(t, off);
        inner[p] = t;
    }
    if (l == 0) {
        double num = inner[0] * inner[1];
        double den = inner[2] * inner[3];
        if (fabs(den) < 1e-9) den = 1e-9;
        double crc = num / den;
        if (fabs(crc) < 1e-9) crc = 1e-9;
        double ratio = crinit[0] / crc;
        scalef[0] = (float)pow(fabs(ratio), 0.25);
    }
}

__global__ void k_scale(float* __restrict__ out, const float* __restrict__ scalef, int total4) {
    int i = blockIdx.x * blockDim.x + threadIdx.x;
    if (i >= total4) return;
    float s = scalef[0];
    float4 t = ((float4*)out)[i];
    t.x *= s; t.y *= s; t.z *= s; t.w *= s;
    ((float4*)out)[i] = t;
}

extern "C" void kernel_launch(void* const* d_in, const int* in_sizes, int n_in,
                              void* d_out, int out_size, void* d_ws, size_t ws_size,
                              hipStream_t stream) {
    const float* x  = (const float*)d_in[0];
    const int*   ei = (const int*)d_in[1];
    const float* Wq = (const float*)d_in[2];
    const float* bq = (const float*)d_in[3];
    const float* Wk = (const float*)d_in[4];
    const float* bk = (const float*)d_in[5];
    const float* Wv = (const float*)d_in[6];
    const float* bv = (const float*)d_in[7];
    const float* Wo = (const float*)d_in[8];
    const float* bo = (const float*)d_in[9];
    float* out = (float*)d_out;

    const int N = in_sizes[0] / 128;
    const int E = in_sizes[1] / 2;
    const size_t NR = (size_t)N * 128;

    float* qn = (float*)d_ws;       // N*128 ; later reused as out_pre
    float* kn = qn + NR;            // N*128
    float* vb = kn + NR;            // N*128
    float* xp = vb + NR;            // N*128 ; region reused after projections:
    float* scores = xp;             //   E*2 floats
    int* counts = (int*)(scores + (size_t)E * 2);
    int* offs   = counts + N;       // N+1
    int* cursor = offs + N + 1;     // N
    int* elist  = cursor + N;       // E
    int* tsum   = elist + E;        // tiles

    double* crinit = (double*)(xp + NR);
    double* psum   = crinit + 1;            // 1024 doubles
    float* pmax    = (float*)(psum + 1024); // 1024 floats
    float* mhead   = pmax + 1024;           // 2
    float* sumf    = mhead + 2;             // 2
    float* scalef  = sumf + 2;              // 1

    float* out_pre = qn;  // reuse

    const int T = (N + 1023) / 1024;

    k_cr_init<<<1, 64, 0, stream>>>(x, crinit);
    k_normx<<<(N * 64 + 255) / 256, 256, 0, stream>>>(x, xp, N);
    k_proj<0><<<512, 256, 0, stream>>>(xp, Wq, bq, qn, N);
    k_proj<1><<<512, 256, 0, stream>>>(xp, Wk, bk, kn, N);
    k_proj<2><<<512, 256, 0, stream>>>(xp, Wv, bv, vb, N);
    k_scores<<<2048, 256, 0, stream>>>(qn, kn, ei, scores, E);
    k_max<<<512, 256, 0, stream>>>(scores, pmax, E);
    k_max2<<<1, 256, 0, stream>>>(pmax, mhead, 512);
    k_expsum<<<512, 256, 0, stream>>>(scores, mhead, psum, E);
    k_sum2<<<1, 256, 0, stream>>>(psum, sumf, 512);
    hipMemsetAsync(counts, 0, (size_t)N * sizeof(int), stream);
    k_hist<<<1024, 256, 0, stream>>>(ei, counts, E);
    k_scan1<<<T, 256, 0, stream>>>(counts, offs, tsum, N);
    k_scan2<<<1, 64, 0, stream>>>(tsum, offs, T, N);
    k_scan3<<<(N + 255) / 256, 256, 0, stream>>>(offs, cursor, tsum, N);
    k_fill<<<1024, 256, 0, stream>>>(ei, cursor, elist, E);
    k_agg<<<(N + 7) / 8, 256, 0, stream>>>(vb, scores, ei, offs, elist, mhead, sumf, out_pre, N, E);
    k_out<<<512, 256, 0, stream>>>(out_pre, Wo, bo, out, N);
    k_crout<<<1, 64, 0, stream>>>(out, crinit, scalef);
    k_scale<<<(N * 16 + 255) / 256, 256, 0, stream>>>(out, scalef, N * 16);
}

// Round 4
// 919.397 us; speedup vs baseline: 1.9464x; 1.8341x over previous
//
#include <hip/hip_runtime.h>
#include <math.h>

#define EPSF 1e-9f
#define INV_SQRT128 0.08838834764831845f

// ---------------- cross-ratio of x rows 0..3 (128 dims) ----------------
__global__ void k_cr_init(const float* __restrict__ x, double* __restrict__ crinit) {
    int l = threadIdx.x; // 64 threads
    const int pa[4] = {0, 1, 0, 1};
    const int pb[4] = {2, 3, 3, 2};
    double inner[4];
    for (int p = 0; p < 4; p++) {
        const float* a = x + pa[p] * 128;
        const float* b = x + pb[p] * 128;
        double s = (double)a[l] * (double)b[l];
        double t = (double)a[l + 64] * (double)b[l + 64];
        s += (l == 63) ? -t : t;  // index 127 is the time coord
        for (int off = 32; off; off >>= 1) s += __shfl_xor(s, off);
        inner[p] = s;
    }
    if (l == 0) {
        double num = inner[0] * inner[1];
        double den = inner[2] * inner[3];
        if (fabs(den) < 1e-9) den = 1e-9;
        crinit[0] = num / den;
    }
}

// ---------------- normalize x rows (127 spatial + 1 time) ----------------
__global__ void k_normx(const float* __restrict__ x, float* __restrict__ xp, int N) {
    int wid = (blockIdx.x * blockDim.x + threadIdx.x) >> 6;
    int l = threadIdx.x & 63;
    if (wid >= N) return;
    const float* r = x + (size_t)wid * 128;
    float a = r[l];
    float b = r[l + 64];
    float pp = a * a + ((l < 63) ? b * b : 0.f);
    for (int off = 32; off; off >>= 1) pp += __shfl_xor(pp, off);
    float nm = fmaxf(sqrtf(pp), EPSF);
    float* o = xp + (size_t)wid * 128;
    o[l] = a / nm;
    o[l + 64] = (l == 63) ? b : b / nm;
}

// ---------------- projection + head-normalize ----------------
// Round-3 lesson: wave-uniform GLOBAL loads (all 64 lanes same address) are NOT
// broadcast-optimized -- each x row cost ~10k cycles through the TA/L1 path
// (k_proj 425us, VALUBusy 16%). LDS same-address reads ARE free broadcasts.
// Structure: 32 rows/block (100000 = 3125*32 exactly), stage x tile coalesced
// into LDS, 4 waves = {head}x{K-half}, 64 weight floats per lane in VGPRs,
// partial sums through LDS, reduce phase does bias+normalize+store.
template<int KIND>  // 0=q (normalize, -time, 1/sqrt128), 1=k (normalize), 2=v
__global__ void __launch_bounds__(256, 1)
k_proj(const float* __restrict__ xp, const float* __restrict__ W,
       const float* __restrict__ bias, float* __restrict__ outp) {
    __shared__ __align__(16) float xs[32 * 128];        // 16 KB x tile
    __shared__ float P[2][2][32][64];                   // [khalf][head][row][lane] 32 KB
    int tid = threadIdx.x;
    int w = tid >> 6, lane = tid & 63;
    int khalf = w & 1, head = w >> 1;
    size_t base = (size_t)blockIdx.x * 32;

    // stage x tile: contiguous 16 KB region, perfectly coalesced
    const float4* g4 = (const float4*)(xp + base * 128);
    float4* xs4 = (float4*)xs;
#pragma unroll
    for (int i = 0; i < 4; i++) xs4[tid + i * 256] = g4[tid + i * 256];

    // weights: my output col = head*64+lane, K range [khalf*64, khalf*64+64)
    float4 wv[16];
    const float4* wp = (const float4*)(W + (size_t)(head * 64 + lane) * 128 + khalf * 64);
#pragma unroll
    for (int j = 0; j < 16; j++) wv[j] = wp[j];

    __syncthreads();

    for (int r = 0; r < 32; r++) {
        const float4* xr = (const float4*)(xs + r * 128 + khalf * 64);
        float a0 = 0.f, a1 = 0.f, a2 = 0.f, a3 = 0.f;
#pragma unroll
        for (int j = 0; j < 16; j += 4) {
            float4 x0 = xr[j], x1 = xr[j + 1], x2 = xr[j + 2], x3 = xr[j + 3];
            a0 = fmaf(x0.x, wv[j].x, a0);
            a0 = fmaf(x0.y, wv[j].y, a0);
            a0 = fmaf(x0.z, wv[j].z, a0);
            a0 = fmaf(x0.w, wv[j].w, a0);
            a1 = fmaf(x1.x, wv[j + 1].x, a1);
            a1 = fmaf(x1.y, wv[j + 1].y, a1);
            a1 = fmaf(x1.z, wv[j + 1].z, a1);
            a1 = fmaf(x1.w, wv[j + 1].w, a1);
            a2 = fmaf(x2.x, wv[j + 2].x, a2);
            a2 = fmaf(x2.y, wv[j + 2].y, a2);
            a2 = fmaf(x2.z, wv[j + 2].z, a2);
            a2 = fmaf(x2.w, wv[j + 2].w, a2);
            a3 = fmaf(x3.x, wv[j + 3].x, a3);
            a3 = fmaf(x3.y, wv[j + 3].y, a3);
            a3 = fmaf(x3.z, wv[j + 3].z, a3);
            a3 = fmaf(x3.w, wv[j + 3].w, a3);
        }
        P[khalf][head][r][lane] = (a0 + a1) + (a2 + a3);
    }
    __syncthreads();

    // reduce: wave w -> head h2 = w>>1, rows [(w&1)*16, +16)
    int h2 = w >> 1, r0 = (w & 1) * 16;
    float br = bias[h2 * 64 + lane];
    for (int rr = 0; rr < 16; rr++) {
        int r = r0 + rr;
        float val = P[0][h2][r][lane] + P[1][h2][r][lane] + br;
        if (KIND < 2) {
            float pp = (lane < 63) ? val * val : 0.f;
            for (int off = 32; off; off >>= 1) pp += __shfl_xor(pp, off);
            float nm = fmaxf(sqrtf(pp), EPSF);
            val = (lane < 63) ? (val / nm) : val;   // keep homogeneous coord
            if (KIND == 0) {
                if (lane == 63) val = -val;          // fold uhg minus into q
                val *= INV_SQRT128;                  // fold 1/sqrt(IN_F) into q
            }
        }
        outp[(base + r) * 128 + h2 * 64 + lane] = val;
    }
}

// ---------------- final GEMM via same LDS-broadcast structure ----------------
// out[n, 0:64] = out_pre[n, 0:128] @ Wo.T + bo. 4 waves = {rowhalf}x{khalf}.
__global__ void __launch_bounds__(256, 1)
k_out2(const float* __restrict__ op, const float* __restrict__ Wo,
       const float* __restrict__ bo, float* __restrict__ out) {
    __shared__ __align__(16) float xs[32 * 128];   // 16 KB
    __shared__ float P[2][32][64];                 // [khalf][row][lane] 16 KB
    int tid = threadIdx.x;
    int w = tid >> 6, lane = tid & 63;
    int khalf = w & 1, rh = w >> 1;
    size_t base = (size_t)blockIdx.x * 32;

    const float4* g4 = (const float4*)(op + base * 128);
    float4* xs4 = (float4*)xs;
#pragma unroll
    for (int i = 0; i < 4; i++) xs4[tid + i * 256] = g4[tid + i * 256];

    float4 wv[16];
    const float4* wp = (const float4*)(Wo + (size_t)lane * 128 + khalf * 64);
#pragma unroll
    for (int j = 0; j < 16; j++) wv[j] = wp[j];

    __syncthreads();

    for (int rr = 0; rr < 16; rr++) {
        int r = rh * 16 + rr;
        const float4* xr = (const float4*)(xs + r * 128 + khalf * 64);
        float a0 = 0.f, a1 = 0.f, a2 = 0.f, a3 = 0.f;
#pragma unroll
        for (int j = 0; j < 16; j += 4) {
            float4 x0 = xr[j], x1 = xr[j + 1], x2 = xr[j + 2], x3 = xr[j + 3];
            a0 = fmaf(x0.x, wv[j].x, a0);
            a0 = fmaf(x0.y, wv[j].y, a0);
            a0 = fmaf(x0.z, wv[j].z, a0);
            a0 = fmaf(x0.w, wv[j].w, a0);
            a1 = fmaf(x1.x, wv[j + 1].x, a1);
            a1 = fmaf(x1.y, wv[j + 1].y, a1);
            a1 = fmaf(x1.z, wv[j + 1].z, a1);
            a1 = fmaf(x1.w, wv[j + 1].w, a1);
            a2 = fmaf(x2.x, wv[j + 2].x, a2);
            a2 = fmaf(x2.y, wv[j + 2].y, a2);
            a2 = fmaf(x2.z, wv[j + 2].z, a2);
            a2 = fmaf(x2.w, wv[j + 2].w, a2);
            a3 = fmaf(x3.x, wv[j + 3].x, a3);
            a3 = fmaf(x3.y, wv[j + 3].y, a3);
            a3 = fmaf(x3.z, wv[j + 3].z, a3);
            a3 = fmaf(x3.w, wv[j + 3].w, a3);
        }
        P[khalf][r][lane] = (a0 + a1) + (a2 + a3);
    }
    __syncthreads();

    float br = bo[lane];
    for (int rr = 0; rr < 8; rr++) {
        int r = w * 8 + rr;
        out[(base + r) * 64 + lane] = P[0][r][lane] + P[1][r][lane] + br;
    }
}

// ---------------- per-edge scores ----------------
// 32 lanes per edge: lanes 0-15 head0, 16-31 head1 (4 floats each).
__global__ void k_scores(const float* __restrict__ qn, const float* __restrict__ kn,
                         const int* __restrict__ ei, float* __restrict__ scores, int E) {
    int g = threadIdx.x >> 5;   // group in block (8)
    int l = threadIdx.x & 31;
    int head = l >> 4;
    int nGroups = (blockDim.x >> 5) * gridDim.x;
    for (int e = blockIdx.x * 8 + g; e < E; e += nGroups) {
        int r = ei[e];
        int c = ei[E + e];
        float4 q4 = ((const float4*)qn)[(size_t)r * 32 + l];
        float4 k4 = ((const float4*)kn)[(size_t)c * 32 + l];
        float p = q4.x * k4.x;
        p = fmaf(q4.y, k4.y, p);
        p = fmaf(q4.z, k4.z, p);
        p = fmaf(q4.w, k4.w, p);
        p += __shfl_xor(p, 1);
        p += __shfl_xor(p, 2);
        p += __shfl_xor(p, 4);
        p += __shfl_xor(p, 8);
        if ((l & 15) == 0) scores[(size_t)e * 2 + head] = p;
    }
}

// ---------------- global max over edges (per head) ----------------
__global__ void k_max(const float* __restrict__ scores, float* __restrict__ pmax, int E) {
    float m0 = -INFINITY, m1 = -INFINITY;
    int stride = blockDim.x * gridDim.x;
    for (int i = blockIdx.x * blockDim.x + threadIdx.x; i < E; i += stride) {
        float2 s = ((const float2*)scores)[i];
        m0 = fmaxf(m0, s.x);
        m1 = fmaxf(m1, s.y);
    }
    for (int off = 32; off; off >>= 1) {
        m0 = fmaxf(m0, __shfl_xor(m0, off));
        m1 = fmaxf(m1, __shfl_xor(m1, off));
    }
    __shared__ float sm[2][4];
    int w = threadIdx.x >> 6;
    if ((threadIdx.x & 63) == 0) { sm[0][w] = m0; sm[1][w] = m1; }
    __syncthreads();
    if (threadIdx.x == 0) {
        for (int i = 1; i < 4; i++) { m0 = fmaxf(m0, sm[0][i]); m1 = fmaxf(m1, sm[1][i]); }
        pmax[blockIdx.x * 2 + 0] = m0;
        pmax[blockIdx.x * 2 + 1] = m1;
    }
}

__global__ void k_max2(const float* __restrict__ pmax, float* __restrict__ mhead, int P) {
    float m0 = -INFINITY, m1 = -INFINITY;
    for (int i = threadIdx.x; i < P; i += blockDim.x) {
        m0 = fmaxf(m0, pmax[2 * i]);
        m1 = fmaxf(m1, pmax[2 * i + 1]);
    }
    for (int off = 32; off; off >>= 1) {
        m0 = fmaxf(m0, __shfl_xor(m0, off));
        m1 = fmaxf(m1, __shfl_xor(m1, off));
    }
    __shared__ float sm[2][4];
    int w = threadIdx.x >> 6;
    if ((threadIdx.x & 63) == 0) { sm[0][w] = m0; sm[1][w] = m1; }
    __syncthreads();
    if (threadIdx.x == 0) {
        for (int i = 1; i < 4; i++) { m0 = fmaxf(m0, sm[0][i]); m1 = fmaxf(m1, sm[1][i]); }
        mhead[0] = m0;
        mhead[1] = m1;
    }
}

// ---------------- global sum of exp (double accumulation) ----------------
__global__ void k_expsum(const float* __restrict__ scores, const float* __restrict__ mhead,
                         double* __restrict__ psum, int E) {
    double s0 = 0.0, s1 = 0.0;
    float m0 = mhead[0], m1 = mhead[1];
    int stride = blockDim.x * gridDim.x;
    for (int i = blockIdx.x * blockDim.x + threadIdx.x; i < E; i += stride) {
        float2 s = ((const float2*)scores)[i];
        s0 += exp((double)(s.x - m0));
        s1 += exp((double)(s.y - m1));
    }
    for (int off = 32; off; off >>= 1) {
        s0 += __shfl_xor(s0, off);
        s1 += __shfl_xor(s1, off);
    }
    __shared__ double sd[2][4];
    int w = threadIdx.x >> 6;
    if ((threadIdx.x & 63) == 0) { sd[0][w] = s0; sd[1][w] = s1; }
    __syncthreads();
    if (threadIdx.x == 0) {
        for (int i = 1; i < 4; i++) { s0 += sd[0][i]; s1 += sd[1][i]; }
        psum[blockIdx.x * 2 + 0] = s0;
        psum[blockIdx.x * 2 + 1] = s1;
    }
}

__global__ void k_sum2(const double* __restrict__ psum, float* __restrict__ sumf, int P) {
    double s0 = 0.0, s1 = 0.0;
    for (int i = threadIdx.x; i < P; i += blockDim.x) {
        s0 += psum[2 * i];
        s1 += psum[2 * i + 1];
    }
    for (int off = 32; off; off >>= 1) {
        s0 += __shfl_xor(s0, off);
        s1 += __shfl_xor(s1, off);
    }
    __shared__ double sd[2][4];
    int w = threadIdx.x >> 6;
    if ((threadIdx.x & 63) == 0) { sd[0][w] = s0; sd[1][w] = s1; }
    __syncthreads();
    if (threadIdx.x == 0) {
        for (int i = 1; i < 4; i++) { s0 += sd[0][i]; s1 += sd[1][i]; }
        sumf[0] = (float)s0;
        sumf[1] = (float)s1;
    }
}

// ---------------- CSR build ----------------
__global__ void k_hist(const int* __restrict__ ei, int* __restrict__ counts, int E) {
    int stride = blockDim.x * gridDim.x;
    for (int e = blockIdx.x * blockDim.x + threadIdx.x; e < E; e += stride)
        atomicAdd(&counts[ei[e]], 1);
}

__global__ void k_scan1(const int* __restrict__ counts, int* __restrict__ offs,
                        int* __restrict__ tsum, int N) {
    __shared__ int sd[256];
    int tile = blockIdx.x;
    int t = threadIdx.x;
    int i0 = tile * 1024 + t * 4;
    int v[4];
    int lsum = 0;
    for (int j = 0; j < 4; j++) {
        int idx = i0 + j;
        v[j] = (idx < N) ? counts[idx] : 0;
        lsum += v[j];
    }
    sd[t] = lsum;
    __syncthreads();
    for (int off = 1; off < 256; off <<= 1) {
        int val = sd[t];
        int add = (t >= off) ? sd[t - off] : 0;
        __syncthreads();
        sd[t] = val + add;
        __syncthreads();
    }
    int excl = (t == 0) ? 0 : sd[t - 1];
    if (t == 255) tsum[tile] = sd[255];
    int run = excl;
    for (int j = 0; j < 4; j++) {
        int idx = i0 + j;
        if (idx < N) offs[idx] = run;
        run += v[j];
    }
}

__global__ void k_scan2(int* __restrict__ tsum, int* __restrict__ offs, int T, int N) {
    if (threadIdx.x == 0) {
        int run = 0;
        for (int i = 0; i < T; i++) {
            int t = tsum[i];
            tsum[i] = run;
            run += t;
        }
        offs[N] = run;
    }
}

__global__ void k_scan3(int* __restrict__ offs, int* __restrict__ cursor,
                        const int* __restrict__ tsum, int N) {
    int i = blockIdx.x * blockDim.x + threadIdx.x;
    if (i < N) {
        int o = offs[i] + tsum[i >> 10];
        offs[i] = o;
        cursor[i] = o;
    }
}

__global__ void k_fill(const int* __restrict__ ei, int* __restrict__ cursor,
                       int* __restrict__ elist, int E) {
    int stride = blockDim.x * gridDim.x;
    for (int e = blockIdx.x * blockDim.x + threadIdx.x; e < E; e += stride) {
        int r = ei[e];
        int p = atomicAdd(&cursor[r], 1);
        elist[p] = e;
    }
}

// ---------------- aggregation: out_pre[n] = sum_e alpha*v[col] ----------------
__global__ void k_agg(const float* __restrict__ vb, const float* __restrict__ scores,
                      const int* __restrict__ ei, const int* __restrict__ offs,
                      const int* __restrict__ elist, const float* __restrict__ mhead,
                      const float* __restrict__ sumf, float* __restrict__ outp,
                      int N, int E) {
    int n = blockIdx.x * 8 + (threadIdx.x >> 5);
    if (n >= N) return;
    int l = threadIdx.x & 31;
    int head = l >> 4;
    float m = mhead[head];
    float sf = sumf[head];
    int s0 = offs[n], s1 = offs[n + 1];
    float4 acc = {0.f, 0.f, 0.f, 0.f};
    for (int i = s0; i < s1; i++) {
        int e = elist[i];
        int c = ei[E + e];
        float sc = scores[(size_t)e * 2 + head];
        float a = expf(sc - m) / sf;
        float4 v4 = ((const float4*)vb)[(size_t)c * 32 + l];
        acc.x = fmaf(v4.x, a, acc.x);
        acc.y = fmaf(v4.y, a, acc.y);
        acc.z = fmaf(v4.z, a, acc.z);
        acc.w = fmaf(v4.w, a, acc.w);
    }
    ((float4*)outp)[(size_t)n * 32 + l] = acc;
}

// ---------------- cross-ratio restore ----------------
__global__ void k_crout(const float* __restrict__ out, const double* __restrict__ crinit,
                        float* __restrict__ scalef) {
    int l = threadIdx.x; // 64
    const int pa[4] = {0, 1, 0, 1};
    const int pb[4] = {2, 3, 3, 2};
    double inner[4];
    for (int p = 0; p < 4; p++) {
        const float* a = out + pa[p] * 64;
        const float* b = out + pb[p] * 64;
        double t = (double)a[l] * (double)b[l];
        if (l == 63) t = -t;
        for (int off = 32; off; off >>= 1) t += __shfl_xor(t, off);
        inner[p] = t;
    }
    if (l == 0) {
        double num = inner[0] * inner[1];
        double den = inner[2] * inner[3];
        if (fabs(den) < 1e-9) den = 1e-9;
        double crc = num / den;
        if (fabs(crc) < 1e-9) crc = 1e-9;
        double ratio = crinit[0] / crc;
        scalef[0] = (float)pow(fabs(ratio), 0.25);
    }
}

__global__ void k_scale(float* __restrict__ out, const float* __restrict__ scalef, int total4) {
    int i = blockIdx.x * blockDim.x + threadIdx.x;
    if (i >= total4) return;
    float s = scalef[0];
    float4 t = ((float4*)out)[i];
    t.x *= s; t.y *= s; t.z *= s; t.w *= s;
    ((float4*)out)[i] = t;
}

extern "C" void kernel_launch(void* const* d_in, const int* in_sizes, int n_in,
                              void* d_out, int out_size, void* d_ws, size_t ws_size,
                              hipStream_t stream) {
    const float* x  = (const float*)d_in[0];
    const int*   ei = (const int*)d_in[1];
    const float* Wq = (const float*)d_in[2];
    const float* bq = (const float*)d_in[3];
    const float* Wk = (const float*)d_in[4];
    const float* bk = (const float*)d_in[5];
    const float* Wv = (const float*)d_in[6];
    const float* bv = (const float*)d_in[7];
    const float* Wo = (const float*)d_in[8];
    const float* bo = (const float*)d_in[9];
    float* out = (float*)d_out;

    const int N = in_sizes[0] / 128;   // 100000 (= 3125 * 32)
    const int E = in_sizes[1] / 2;
    const size_t NR = (size_t)N * 128;
    const int NB = N / 32;             // blocks for the 32-row GEMM kernels

    float* qn = (float*)d_ws;       // N*128 ; later reused as out_pre
    float* kn = qn + NR;            // N*128
    float* vb = kn + NR;            // N*128
    float* xp = vb + NR;            // N*128 ; region reused after projections:
    float* scores = xp;             //   E*2 floats
    int* counts = (int*)(scores + (size_t)E * 2);
    int* offs   = counts + N;       // N+1
    int* cursor = offs + N + 1;     // N
    int* elist  = cursor + N;       // E
    int* tsum   = elist + E;        // tiles

    double* crinit = (double*)(xp + NR);
    double* psum   = crinit + 1;            // 1024 doubles
    float* pmax    = (float*)(psum + 1024); // 1024 floats
    float* mhead   = pmax + 1024;           // 2
    float* sumf    = mhead + 2;             // 2
    float* scalef  = sumf + 2;              // 1

    float* out_pre = qn;  // reuse

    const int T = (N + 1023) / 1024;

    k_cr_init<<<1, 64, 0, stream>>>(x, crinit);
    k_normx<<<(N * 64 + 255) / 256, 256, 0, stream>>>(x, xp, N);
    k_proj<0><<<NB, 256, 0, stream>>>(xp, Wq, bq, qn);
    k_proj<1><<<NB, 256, 0, stream>>>(xp, Wk, bk, kn);
    k_proj<2><<<NB, 256, 0, stream>>>(xp, Wv, bv, vb);
    k_scores<<<2048, 256, 0, stream>>>(qn, kn, ei, scores, E);
    k_max<<<512, 256, 0, stream>>>(scores, pmax, E);
    k_max2<<<1, 256, 0, stream>>>(pmax, mhead, 512);
    k_expsum<<<512, 256, 0, stream>>>(scores, mhead, psum, E);
    k_sum2<<<1, 256, 0, stream>>>(psum, sumf, 512);
    hipMemsetAsync(counts, 0, (size_t)N * sizeof(int), stream);
    k_hist<<<1024, 256, 0, stream>>>(ei, counts, E);
    k_scan1<<<T, 256, 0, stream>>>(counts, offs, tsum, N);
    k_scan2<<<1, 64, 0, stream>>>(tsum, offs, T, N);
    k_scan3<<<(N + 255) / 256, 256, 0, stream>>>(offs, cursor, tsum, N);
    k_fill<<<1024, 256, 0, stream>>>(ei, cursor, elist, E);
    k_agg<<<(N + 7) / 8, 256, 0, stream>>>(vb, scores, ei, offs, elist, mhead, sumf, out_pre, N, E);
    k_out2<<<NB, 256, 0, stream>>>(out_pre, Wo, bo, out);
    k_crout<<<1, 64, 0, stream>>>(out, crinit, scalef);
    k_scale<<<(N * 16 + 255) / 256, 256, 0, stream>>>(out, scalef, N * 16);
}

// Round 5
// 820.093 us; speedup vs baseline: 2.1821x; 1.1211x over previous
//
#include <hip/hip_runtime.h>
#include <math.h>

#define EPSF 1e-9f
#define INV_SQRT128 0.08838834764831845f

// ---------------- cross-ratio of x rows 0..3 (128 dims) ----------------
__global__ void k_cr_init(const float* __restrict__ x, double* __restrict__ crinit) {
    int l = threadIdx.x; // 64 threads
    const int pa[4] = {0, 1, 0, 1};
    const int pb[4] = {2, 3, 3, 2};
    double inner[4];
    for (int p = 0; p < 4; p++) {
        const float* a = x + pa[p] * 128;
        const float* b = x + pb[p] * 128;
        double s = (double)a[l] * (double)b[l];
        double t = (double)a[l + 64] * (double)b[l + 64];
        s += (l == 63) ? -t : t;  // index 127 is the time coord
        for (int off = 32; off; off >>= 1) s += __shfl_xor(s, off);
        inner[p] = s;
    }
    if (l == 0) {
        double num = inner[0] * inner[1];
        double den = inner[2] * inner[3];
        if (fabs(den) < 1e-9) den = 1e-9;
        crinit[0] = num / den;
    }
}

// ---------------- normalize x rows (127 spatial + 1 time) ----------------
__global__ void k_normx(const float* __restrict__ x, float* __restrict__ xp, int N) {
    int wid = (blockIdx.x * blockDim.x + threadIdx.x) >> 6;
    int l = threadIdx.x & 63;
    if (wid >= N) return;
    const float* r = x + (size_t)wid * 128;
    float a = r[l];
    float b = r[l + 64];
    float pp = a * a + ((l < 63) ? b * b : 0.f);
    for (int off = 32; off; off >>= 1) pp += __shfl_xor(pp, off);
    float nm = fmaxf(sqrtf(pp), EPSF);
    float* o = xp + (size_t)wid * 128;
    o[l] = a / nm;
    o[l + 64] = (l == 63) ? b : b / nm;
}

// ---------------- projection + head-normalize ----------------
// LDS-broadcast structure (round-4 win): 32 rows/block, x tile staged coalesced
// into LDS (same-address LDS reads are free broadcasts; wave-uniform GLOBAL
// loads are not), 4 waves = {head}x{K-half}, weights in VGPRs, partials via LDS.
template<int KIND>  // 0=q (normalize, -time, 1/sqrt128), 1=k (normalize), 2=v
__global__ void __launch_bounds__(256, 1)
k_proj(const float* __restrict__ xp, const float* __restrict__ W,
       const float* __restrict__ bias, float* __restrict__ outp) {
    __shared__ __align__(16) float xs[32 * 128];        // 16 KB x tile
    __shared__ float P[2][2][32][64];                   // [khalf][head][row][lane] 32 KB
    int tid = threadIdx.x;
    int w = tid >> 6, lane = tid & 63;
    int khalf = w & 1, head = w >> 1;
    size_t base = (size_t)blockIdx.x * 32;

    const float4* g4 = (const float4*)(xp + base * 128);
    float4* xs4 = (float4*)xs;
#pragma unroll
    for (int i = 0; i < 4; i++) xs4[tid + i * 256] = g4[tid + i * 256];

    float4 wv[16];
    const float4* wp = (const float4*)(W + (size_t)(head * 64 + lane) * 128 + khalf * 64);
#pragma unroll
    for (int j = 0; j < 16; j++) wv[j] = wp[j];

    __syncthreads();

    for (int r = 0; r < 32; r++) {
        const float4* xr = (const float4*)(xs + r * 128 + khalf * 64);
        float a0 = 0.f, a1 = 0.f, a2 = 0.f, a3 = 0.f;
#pragma unroll
        for (int j = 0; j < 16; j += 4) {
            float4 x0 = xr[j], x1 = xr[j + 1], x2 = xr[j + 2], x3 = xr[j + 3];
            a0 = fmaf(x0.x, wv[j].x, a0);
            a0 = fmaf(x0.y, wv[j].y, a0);
            a0 = fmaf(x0.z, wv[j].z, a0);
            a0 = fmaf(x0.w, wv[j].w, a0);
            a1 = fmaf(x1.x, wv[j + 1].x, a1);
            a1 = fmaf(x1.y, wv[j + 1].y, a1);
            a1 = fmaf(x1.z, wv[j + 1].z, a1);
            a1 = fmaf(x1.w, wv[j + 1].w, a1);
            a2 = fmaf(x2.x, wv[j + 2].x, a2);
            a2 = fmaf(x2.y, wv[j + 2].y, a2);
            a2 = fmaf(x2.z, wv[j + 2].z, a2);
            a2 = fmaf(x2.w, wv[j + 2].w, a2);
            a3 = fmaf(x3.x, wv[j + 3].x, a3);
            a3 = fmaf(x3.y, wv[j + 3].y, a3);
            a3 = fmaf(x3.z, wv[j + 3].z, a3);
            a3 = fmaf(x3.w, wv[j + 3].w, a3);
        }
        P[khalf][head][r][lane] = (a0 + a1) + (a2 + a3);
    }
    __syncthreads();

    int h2 = w >> 1, r0 = (w & 1) * 16;
    float br = bias[h2 * 64 + lane];
    for (int rr = 0; rr < 16; rr++) {
        int r = r0 + rr;
        float val = P[0][h2][r][lane] + P[1][h2][r][lane] + br;
        if (KIND < 2) {
            float pp = (lane < 63) ? val * val : 0.f;
            for (int off = 32; off; off >>= 1) pp += __shfl_xor(pp, off);
            float nm = fmaxf(sqrtf(pp), EPSF);
            val = (lane < 63) ? (val / nm) : val;   // keep homogeneous coord
            if (KIND == 0) {
                if (lane == 63) val = -val;          // fold uhg minus into q
                val *= INV_SQRT128;                  // fold 1/sqrt(IN_F) into q
            }
        }
        outp[(base + r) * 128 + h2 * 64 + lane] = val;
    }
}

// ---------------- CSR build ----------------
__global__ void k_hist(const int* __restrict__ ei, int* __restrict__ counts, int E) {
    int stride = blockDim.x * gridDim.x;
    for (int e = blockIdx.x * blockDim.x + threadIdx.x; e < E; e += stride)
        atomicAdd(&counts[ei[e]], 1);
}

__global__ void k_scan1(const int* __restrict__ counts, int* __restrict__ offs,
                        int* __restrict__ tsum, int N) {
    __shared__ int sd[256];
    int tile = blockIdx.x;
    int t = threadIdx.x;
    int i0 = tile * 1024 + t * 4;
    int v[4];
    int lsum = 0;
    for (int j = 0; j < 4; j++) {
        int idx = i0 + j;
        v[j] = (idx < N) ? counts[idx] : 0;
        lsum += v[j];
    }
    sd[t] = lsum;
    __syncthreads();
    for (int off = 1; off < 256; off <<= 1) {
        int val = sd[t];
        int add = (t >= off) ? sd[t - off] : 0;
        __syncthreads();
        sd[t] = val + add;
        __syncthreads();
    }
    int excl = (t == 0) ? 0 : sd[t - 1];
    if (t == 255) tsum[tile] = sd[255];
    int run = excl;
    for (int j = 0; j < 4; j++) {
        int idx = i0 + j;
        if (idx < N) offs[idx] = run;
        run += v[j];
    }
}

__global__ void k_scan2(int* __restrict__ tsum, int* __restrict__ offs, int T, int N) {
    if (threadIdx.x == 0) {
        int run = 0;
        for (int i = 0; i < T; i++) {
            int t = tsum[i];
            tsum[i] = run;
            run += t;
        }
        offs[N] = run;
    }
}

__global__ void k_scan3(int* __restrict__ offs, int* __restrict__ cursor,
                        const int* __restrict__ tsum, int N) {
    int i = blockIdx.x * blockDim.x + threadIdx.x;
    if (i < N) {
        int o = offs[i] + tsum[i >> 10];
        offs[i] = o;
        cursor[i] = o;
    }
}

// stores the COLUMN id in CSR order (no edge-id indirection downstream)
__global__ void k_fill(const int* __restrict__ ei, int* __restrict__ cursor,
                       int* __restrict__ ccol, int E) {
    int stride = blockDim.x * gridDim.x;
    for (int e = blockIdx.x * blockDim.x + threadIdx.x; e < E; e += stride) {
        int r = ei[e];
        int p = atomicAdd(&cursor[r], 1);
        ccol[p] = ei[E + e];
    }
}

// ---------------- scores in CSR order + per-block expsum partials ----------------
// q side is sequential (one row per node); k side is the unavoidable random gather.
// No max subtraction: |score| <~ 1 analytically (unit spatial parts, /sqrt(128)),
// so exp() cannot overflow and softmax's max-shift cancels exactly.
__global__ void k_scores_csr(const float* __restrict__ qn, const float* __restrict__ kn,
                             const int* __restrict__ offs, const int* __restrict__ ccol,
                             float* __restrict__ sc, double* __restrict__ psum, int N) {
    int g = threadIdx.x >> 5;            // 8 groups of 32 lanes
    int l = threadIdx.x & 31;
    int head = l >> 4;
    int n = blockIdx.x * 8 + g;
    double esum = 0.0;
    if (n < N) {
        float4 q4 = ((const float4*)qn)[(size_t)n * 32 + l];
        int s0 = offs[n], s1 = offs[n + 1];
        for (int i = s0; i < s1; i++) {
            int c = ccol[i];
            float4 k4 = ((const float4*)kn)[(size_t)c * 32 + l];
            float p = q4.x * k4.x;
            p = fmaf(q4.y, k4.y, p);
            p = fmaf(q4.z, k4.z, p);
            p = fmaf(q4.w, k4.w, p);
            p += __shfl_xor(p, 1);
            p += __shfl_xor(p, 2);
            p += __shfl_xor(p, 4);
            p += __shfl_xor(p, 8);
            if ((l & 15) == 0) {
                sc[(size_t)i * 2 + head] = p;
                esum += exp((double)p);
            }
        }
    }
    __shared__ double sd[2][8];
    if ((l & 15) == 0) sd[head][g] = esum;
    __syncthreads();
    if (threadIdx.x < 2) {
        double s = 0.0;
        for (int i = 0; i < 8; i++) s += sd[threadIdx.x][i];
        psum[(size_t)blockIdx.x * 2 + threadIdx.x] = s;
    }
}

// deterministic reduce of per-block partials -> sumf[2] (double)
__global__ void k_sum2(const double* __restrict__ psum, double* __restrict__ sumf, int P) {
    double s0 = 0.0, s1 = 0.0;
    for (int i = threadIdx.x; i < P; i += blockDim.x) {
        s0 += psum[2 * i];
        s1 += psum[2 * i + 1];
    }
    for (int off = 32; off; off >>= 1) {
        s0 += __shfl_xor(s0, off);
        s1 += __shfl_xor(s1, off);
    }
    __shared__ double sd[2][4];
    int w = threadIdx.x >> 6;
    if ((threadIdx.x & 63) == 0) { sd[0][w] = s0; sd[1][w] = s1; }
    __syncthreads();
    if (threadIdx.x == 0) {
        for (int i = 1; i < 4; i++) { s0 += sd[0][i]; s1 += sd[1][i]; }
        sumf[0] = s0;
        sumf[1] = s1;
    }
}

// ---------------- aggregation (CSR order, unnormalized): U[n] = sum exp(s)*v[col] ----------------
__global__ void k_agg_csr(const float* __restrict__ vb, const float* __restrict__ sc,
                          const int* __restrict__ offs, const int* __restrict__ ccol,
                          float* __restrict__ U, int N) {
    int g = threadIdx.x >> 5;
    int l = threadIdx.x & 31;
    int head = l >> 4;
    int n = blockIdx.x * 8 + g;
    if (n >= N) return;
    int s0 = offs[n], s1 = offs[n + 1];
    float4 acc = {0.f, 0.f, 0.f, 0.f};
    for (int i = s0; i < s1; i++) {
        int c = ccol[i];
        float a = expf(sc[(size_t)i * 2 + head]);
        float4 v4 = ((const float4*)vb)[(size_t)c * 32 + l];
        acc.x = fmaf(v4.x, a, acc.x);
        acc.y = fmaf(v4.y, a, acc.y);
        acc.z = fmaf(v4.z, a, acc.z);
        acc.w = fmaf(v4.w, a, acc.w);
    }
    ((float4*)U)[(size_t)n * 32 + l] = acc;
}

// ---------------- rows 0-3 of out + cross-ratio scale factor ----------------
// out rows 0-3 (unscaled) determine cr_cur; scalef applied by k_out2 to all rows.
__global__ void k_crout4(const float* __restrict__ U, const float* __restrict__ Wo,
                         const float* __restrict__ bo, const double* __restrict__ sumf,
                         const double* __restrict__ crinit, float* __restrict__ scalef) {
    __shared__ float xs[4 * 128];
    __shared__ float o4[4 * 64];
    int tid = threadIdx.x;  // 256
    xs[tid] = U[tid];
    xs[tid + 256] = U[tid + 256];
    __syncthreads();
    int w = tid >> 6, o = tid & 63;
    float si0 = (float)(1.0 / sumf[0]);
    float si1 = (float)(1.0 / sumf[1]);
    const float* xr = xs + w * 128;
    const float* wr = Wo + (size_t)o * 128;
    float d0 = 0.f, d1 = 0.f;
    for (int j = 0; j < 64; j++) d0 = fmaf(xr[j], wr[j], d0);
    for (int j = 64; j < 128; j++) d1 = fmaf(xr[j], wr[j], d1);
    o4[w * 64 + o] = d0 * si0 + d1 * si1 + bo[o];
    __syncthreads();
    if (tid < 64) {
        int l = tid;
        const int pa[4] = {0, 1, 0, 1};
        const int pb[4] = {2, 3, 3, 2};
        double inner[4];
        for (int p = 0; p < 4; p++) {
            double t = (double)o4[pa[p] * 64 + l] * (double)o4[pb[p] * 64 + l];
            if (l == 63) t = -t;
            for (int off = 32; off; off >>= 1) t += __shfl_xor(t, off);
            inner[p] = t;
        }
        if (l == 0) {
            double num = inner[0] * inner[1];
            double den = inner[2] * inner[3];
            if (fabs(den) < 1e-9) den = 1e-9;
            double crc = num / den;
            if (fabs(crc) < 1e-9) crc = 1e-9;
            double ratio = crinit[0] / crc;
            scalef[0] = (float)pow(fabs(ratio), 0.25);
        }
    }
}

// ---------------- final GEMM: out = ((U/sumf) @ Wo.T + bo) * scalef ----------------
// LDS-broadcast structure; per-head 1/sumf folds into the K-half partials
// (khalf boundary == head boundary), cross-ratio scale folds into the epilogue.
__global__ void __launch_bounds__(256, 1)
k_out2(const float* __restrict__ op, const float* __restrict__ Wo,
       const float* __restrict__ bo, const double* __restrict__ sumf,
       const float* __restrict__ scalef, float* __restrict__ out) {
    __shared__ __align__(16) float xs[32 * 128];   // 16 KB
    __shared__ float P[2][32][64];                 // [khalf][row][lane] 16 KB
    int tid = threadIdx.x;
    int w = tid >> 6, lane = tid & 63;
    int khalf = w & 1, rh = w >> 1;
    size_t base = (size_t)blockIdx.x * 32;

    const float4* g4 = (const float4*)(op + base * 128);
    float4* xs4 = (float4*)xs;
#pragma unroll
    for (int i = 0; i < 4; i++) xs4[tid + i * 256] = g4[tid + i * 256];

    float4 wv[16];
    const float4* wp = (const float4*)(Wo + (size_t)lane * 128 + khalf * 64);
#pragma unroll
    for (int j = 0; j < 16; j++) wv[j] = wp[j];

    __syncthreads();

    for (int rr = 0; rr < 16; rr++) {
        int r = rh * 16 + rr;
        const float4* xr = (const float4*)(xs + r * 128 + khalf * 64);
        float a0 = 0.f, a1 = 0.f, a2 = 0.f, a3 = 0.f;
#pragma unroll
        for (int j = 0; j < 16; j += 4) {
            float4 x0 = xr[j], x1 = xr[j + 1], x2 = xr[j + 2], x3 = xr[j + 3];
            a0 = fmaf(x0.x, wv[j].x, a0);
            a0 = fmaf(x0.y, wv[j].y, a0);
            a0 = fmaf(x0.z, wv[j].z, a0);
            a0 = fmaf(x0.w, wv[j].w, a0);
            a1 = fmaf(x1.x, wv[j + 1].x, a1);
            a1 = fmaf(x1.y, wv[j + 1].y, a1);
            a1 = fmaf(x1.z, wv[j + 1].z, a1);
            a1 = fmaf(x1.w, wv[j + 1].w, a1);
            a2 = fmaf(x2.x, wv[j + 2].x, a2);
            a2 = fmaf(x2.y, wv[j + 2].y, a2);
            a2 = fmaf(x2.z, wv[j + 2].z, a2);
            a2 = fmaf(x2.w, wv[j + 2].w, a2);
            a3 = fmaf(x3.x, wv[j + 3].x, a3);
            a3 = fmaf(x3.y, wv[j + 3].y, a3);
            a3 = fmaf(x3.z, wv[j + 3].z, a3);
            a3 = fmaf(x3.w, wv[j + 3].w, a3);
        }
        P[khalf][r][lane] = (a0 + a1) + (a2 + a3);
    }
    __syncthreads();

    float si0 = (float)(1.0 / sumf[0]);
    float si1 = (float)(1.0 / sumf[1]);
    float sf = scalef[0];
    float br = bo[lane];
    for (int rr = 0; rr < 8; rr++) {
        int r = w * 8 + rr;
        out[(base + r) * 64 + lane] = (P[0][r][lane] * si0 + P[1][r][lane] * si1 + br) * sf;
    }
}

extern "C" void kernel_launch(void* const* d_in, const int* in_sizes, int n_in,
                              void* d_out, int out_size, void* d_ws, size_t ws_size,
                              hipStream_t stream) {
    const float* x  = (const float*)d_in[0];
    const int*   ei = (const int*)d_in[1];
    const float* Wq = (const float*)d_in[2];
    const float* bq = (const float*)d_in[3];
    const float* Wk = (const float*)d_in[4];
    const float* bk = (const float*)d_in[5];
    const float* Wv = (const float*)d_in[6];
    const float* bv = (const float*)d_in[7];
    const float* Wo = (const float*)d_in[8];
    const float* bo = (const float*)d_in[9];
    float* out = (float*)d_out;

    const int N = in_sizes[0] / 128;   // 100000 (= 3125 * 32)
    const int E = in_sizes[1] / 2;
    const size_t NR = (size_t)N * 128;
    const int NB = N / 32;             // 3125 blocks for 32-row GEMM kernels
    const int GB = (N + 7) / 8;        // 12500 blocks for CSR gather kernels

    float* qn = (float*)d_ws;       // N*128 ; reused as U (out_pre) after scores
    float* kn = qn + NR;            // N*128
    float* vb = kn + NR;            // N*128
    float* xp = vb + NR;            // N*128 ; region reused after projections:
    int* counts = (int*)xp;                 // N
    int* offs   = counts + N;               // N+2 (pad keeps psum 8B-aligned)
    int* cursor = offs + N + 2;             // N
    int* ccol   = cursor + N;               // E (column ids in CSR order)
    float* sc   = (float*)(ccol + E);       // E*2 scores in CSR order
    double* psum = (double*)(sc + (size_t)E * 2);  // GB*2 partial expsums
    int* tsum   = (int*)(psum + (size_t)GB * 2);   // scan tiles

    double* crinit = (double*)(xp + NR);
    double* sumf   = crinit + 1;            // 2 doubles
    float* scalef  = (float*)(sumf + 2);    // 1

    float* U = qn;  // reuse q buffer as aggregation output

    const int T = (N + 1023) / 1024;

    k_cr_init<<<1, 64, 0, stream>>>(x, crinit);
    k_normx<<<(N * 64 + 255) / 256, 256, 0, stream>>>(x, xp, N);
    k_proj<0><<<NB, 256, 0, stream>>>(xp, Wq, bq, qn);
    k_proj<1><<<NB, 256, 0, stream>>>(xp, Wk, bk, kn);
    k_proj<2><<<NB, 256, 0, stream>>>(xp, Wv, bv, vb);
    hipMemsetAsync(counts, 0, (size_t)N * sizeof(int), stream);
    k_hist<<<1024, 256, 0, stream>>>(ei, counts, E);
    k_scan1<<<T, 256, 0, stream>>>(counts, offs, tsum, N);
    k_scan2<<<1, 64, 0, stream>>>(tsum, offs, T, N);
    k_scan3<<<(N + 255) / 256, 256, 0, stream>>>(offs, cursor, tsum, N);
    k_fill<<<1024, 256, 0, stream>>>(ei, cursor, ccol, E);
    k_scores_csr<<<GB, 256, 0, stream>>>(qn, kn, offs, ccol, sc, psum, N);
    k_sum2<<<1, 256, 0, stream>>>(psum, sumf, GB);
    k_agg_csr<<<GB, 256, 0, stream>>>(vb, sc, offs, ccol, U, N);
    k_crout4<<<1, 256, 0, stream>>>(U, Wo, bo, sumf, crinit, scalef);
    k_out2<<<NB, 256, 0, stream>>>(U, Wo, bo, sumf, scalef, out);
}

// Round 6
// 641.519 us; speedup vs baseline: 2.7895x; 1.2784x over previous
//
#include <hip/hip_runtime.h>
#include <math.h>

#define EPSF 1e-9f
#define INV_SQRT128 0.08838834764831845f

// LDS swizzles (indices in float4 units) to spread banks at the bw floor
#define XS(r, kc)  ((r) * 32 + ((kc) ^ (((r) >> 3) & 7)))   // kc < 32
#define WSQ(c, kc) ((c) * 8  + ((kc) ^ (((c) >> 2) & 7)))   // kc < 8  (K-quarter)
#define XS2(r, kc) ((r) * 32 + ((kc) ^ (((r) >> 2) & 7)))   // kc < 32
#define WS2(c, kc) ((c) * 16 + ((kc) ^ (((c) >> 2) & 7)))   // kc < 16 (K-half)

// ---------------- cross-ratio of x rows 0..3 (128 dims) ----------------
__global__ void k_cr_init(const float* __restrict__ x, double* __restrict__ crinit) {
    int l = threadIdx.x; // 64 threads
    const int pa[4] = {0, 1, 0, 1};
    const int pb[4] = {2, 3, 3, 2};
    double inner[4];
    for (int p = 0; p < 4; p++) {
        const float* a = x + pa[p] * 128;
        const float* b = x + pb[p] * 128;
        double s = (double)a[l] * (double)b[l];
        double t = (double)a[l + 64] * (double)b[l + 64];
        s += (l == 63) ? -t : t;  // index 127 is the time coord
        for (int off = 32; off; off >>= 1) s += __shfl_xor(s, off);
        inner[p] = s;
    }
    if (l == 0) {
        double num = inner[0] * inner[1];
        double den = inner[2] * inner[3];
        if (fabs(den) < 1e-9) den = 1e-9;
        crinit[0] = num / den;
    }
}

// ---------------- normalize x rows (127 spatial + 1 time) ----------------
__global__ void k_normx(const float* __restrict__ x, float* __restrict__ xp, int N) {
    int wid = (blockIdx.x * blockDim.x + threadIdx.x) >> 6;
    int l = threadIdx.x & 63;
    if (wid >= N) return;
    const float* r = x + (size_t)wid * 128;
    float a = r[l];
    float b = r[l + 64];
    float pp = a * a + ((l < 63) ? b * b : 0.f);
    for (int off = 32; off; off >>= 1) pp += __shfl_xor(pp, off);
    float nm = fmaxf(sqrtf(pp), EPSF);
    float* o = xp + (size_t)wid * 128;
    o[l] = a / nm;
    o[l + 64] = (l == 63) ? b : b / nm;
}

// ---------------- projection + head-normalize: register-tiled GEMM ----------------
// Round-5 lesson: broadcast-style (1 lane = 1 col) costs 4 B of LDS return
// traffic per FMA -> 83us LDS floor per kind. Register tiling (8 rows x 4 cols
// per lane, both operands from LDS) cuts it to 1.5 B/FMA.
// M=64 rows/block; xs[64][128] swizzled (32KB) + W K-quarter tile (16KB,
// restaged 4x) = 48KB LDS -> 3 blocks/CU. rg=tid>>5 (8x8 rows), cg=tid&31 (32x4 cols).
template<int KIND>  // 0=q (normalize, -time, 1/sqrt128), 1=k (normalize), 2=v
__global__ void __launch_bounds__(256, 2)
k_proj(const float* __restrict__ xp, const float* __restrict__ W,
       const float* __restrict__ bias, float* __restrict__ outp,
       int ostride, int ooff, int N) {
    __shared__ float4 xs4[64 * 32];   // 32 KB
    __shared__ float4 ws4[128 * 8];   // 16 KB (one K-quarter of W)
    int tid = threadIdx.x;
    int rg = tid >> 5;       // 8 row-groups x 8 rows
    int cg = tid & 31;       // 32 col-groups x 4 cols
    int base = blockIdx.x * 64;

    const float4* xp4 = (const float4*)xp;
    const float4* W4 = (const float4*)W;

    // stage x tile (guarded, zeros past N)
#pragma unroll
    for (int i2 = 0; i2 < 8; i2++) {
        int idx = tid + i2 * 256;
        int r = idx >> 5, kc = idx & 31;
        int row = base + r;
        float4 v = {0.f, 0.f, 0.f, 0.f};
        if (row < N) v = xp4[(size_t)row * 32 + kc];
        xs4[XS(r, kc)] = v;
    }

    float acc[8][4];
#pragma unroll
    for (int i = 0; i < 8; i++)
#pragma unroll
        for (int j = 0; j < 4; j++) acc[i][j] = 0.f;

    for (int kp = 0; kp < 4; kp++) {
        __syncthreads();
#pragma unroll
        for (int i2 = 0; i2 < 4; i2++) {
            int idx = tid + i2 * 256;
            int c = idx >> 3, kc2 = idx & 7;
            ws4[WSQ(c, kc2)] = W4[(size_t)c * 32 + kp * 8 + kc2];
        }
        __syncthreads();
        for (int kc2 = 0; kc2 < 8; kc2++) {
            int kc = kp * 8 + kc2;
            float4 xa[8], wb[4];
#pragma unroll
            for (int i = 0; i < 8; i++) xa[i] = xs4[XS(rg * 8 + i, kc)];
#pragma unroll
            for (int j = 0; j < 4; j++) wb[j] = ws4[WSQ(cg * 4 + j, kc2)];
#pragma unroll
            for (int i = 0; i < 8; i++)
#pragma unroll
                for (int j = 0; j < 4; j++) {
                    acc[i][j] = fmaf(xa[i].x, wb[j].x, acc[i][j]);
                    acc[i][j] = fmaf(xa[i].y, wb[j].y, acc[i][j]);
                    acc[i][j] = fmaf(xa[i].z, wb[j].z, acc[i][j]);
                    acc[i][j] = fmaf(xa[i].w, wb[j].w, acc[i][j]);
                }
        }
    }

    // epilogue: +bias, per-(row,head) normalize over 63 spatial cols
    float4 bb = ((const float4*)bias)[cg];
    bool istime = ((cg & 15) == 15);  // col cg*4+3 is the head's time coord
#pragma unroll
    for (int i = 0; i < 8; i++) {
        int row = base + rg * 8 + i;
        float v0 = acc[i][0] + bb.x;
        float v1 = acc[i][1] + bb.y;
        float v2 = acc[i][2] + bb.z;
        float v3 = acc[i][3] + bb.w;
        if (KIND < 2) {
            float ss = v0 * v0 + v1 * v1 + v2 * v2 + (istime ? 0.f : v3 * v3);
            ss += __shfl_xor(ss, 1);
            ss += __shfl_xor(ss, 2);
            ss += __shfl_xor(ss, 4);
            ss += __shfl_xor(ss, 8);
            float rn = 1.f / fmaxf(sqrtf(ss), EPSF);
            v0 *= rn; v1 *= rn; v2 *= rn;
            if (!istime) v3 *= rn;
            if (KIND == 0) {
                if (istime) v3 = -v3;       // fold uhg minus into q
                v0 *= INV_SQRT128; v1 *= INV_SQRT128;
                v2 *= INV_SQRT128; v3 *= INV_SQRT128;
            }
        }
        if (row < N) {
            float4 o = {v0, v1, v2, v3};
            ((float4*)(outp + (size_t)row * ostride + ooff))[cg] = o;
        }
    }
}

// ---------------- CSR build ----------------
__global__ void k_hist(const int* __restrict__ ei, int* __restrict__ counts, int E) {
    int stride = blockDim.x * gridDim.x;
    for (int e = blockIdx.x * blockDim.x + threadIdx.x; e < E; e += stride)
        atomicAdd(&counts[ei[e]], 1);
}

__global__ void k_scan1(const int* __restrict__ counts, int* __restrict__ offs,
                        int* __restrict__ tsum, int N) {
    __shared__ int sd[256];
    int tile = blockIdx.x;
    int t = threadIdx.x;
    int i0 = tile * 1024 + t * 4;
    int v[4];
    int lsum = 0;
    for (int j = 0; j < 4; j++) {
        int idx = i0 + j;
        v[j] = (idx < N) ? counts[idx] : 0;
        lsum += v[j];
    }
    sd[t] = lsum;
    __syncthreads();
    for (int off = 1; off < 256; off <<= 1) {
        int val = sd[t];
        int add = (t >= off) ? sd[t - off] : 0;
        __syncthreads();
        sd[t] = val + add;
        __syncthreads();
    }
    int excl = (t == 0) ? 0 : sd[t - 1];
    if (t == 255) tsum[tile] = sd[255];
    int run = excl;
    for (int j = 0; j < 4; j++) {
        int idx = i0 + j;
        if (idx < N) offs[idx] = run;
        run += v[j];
    }
}

__global__ void k_scan2(int* __restrict__ tsum, int* __restrict__ offs, int T, int N) {
    if (threadIdx.x == 0) {
        int run = 0;
        for (int i = 0; i < T; i++) {
            int t = tsum[i];
            tsum[i] = run;
            run += t;
        }
        offs[N] = run;
    }
}

__global__ void k_scan3(int* __restrict__ offs, int* __restrict__ cursor,
                        const int* __restrict__ tsum, int N) {
    int i = blockIdx.x * blockDim.x + threadIdx.x;
    if (i < N) {
        int o = offs[i] + tsum[i >> 10];
        offs[i] = o;
        cursor[i] = o;
    }
}

// stores the COLUMN id in CSR order
__global__ void k_fill(const int* __restrict__ ei, int* __restrict__ cursor,
                       int* __restrict__ ccol, int E) {
    int stride = blockDim.x * gridDim.x;
    for (int e = blockIdx.x * blockDim.x + threadIdx.x; e < E; e += stride) {
        int r = ei[e];
        int p = atomicAdd(&cursor[r], 1);
        ccol[p] = ei[E + e];
    }
}

// ---------------- fused edge pass: scores + exp + aggregate (unnormalized) ----------------
// kv[n] = [k-row 128f | v-row 128f] so each edge's gather is one 256B-local region.
// No max subtraction (|score| <~ 1 analytically). esum accumulates (double)expf(s)
// -- numerator and denominator use the same exp, and no slow double-exp per edge.
__global__ void k_edge(const float* __restrict__ qn, const float* __restrict__ kv,
                       const int* __restrict__ offs, const int* __restrict__ ccol,
                       float* __restrict__ U, double* __restrict__ psum, int N) {
    int g = threadIdx.x >> 5;            // 8 groups of 32 lanes
    int l = threadIdx.x & 31;
    int head = l >> 4;
    int n = blockIdx.x * 8 + g;
    double esum = 0.0;
    if (n < N) {
        float4 q4 = ((const float4*)qn)[(size_t)n * 32 + l];
        int s0 = offs[n], s1 = offs[n + 1];
        float4 acc = {0.f, 0.f, 0.f, 0.f};
        const float4* kv4 = (const float4*)kv;
        for (int i = s0; i < s1; i++) {
            int c = ccol[i];
            float4 k4 = kv4[(size_t)c * 64 + l];
            float4 v4 = kv4[(size_t)c * 64 + 32 + l];
            float p = q4.x * k4.x;
            p = fmaf(q4.y, k4.y, p);
            p = fmaf(q4.z, k4.z, p);
            p = fmaf(q4.w, k4.w, p);
            p += __shfl_xor(p, 1);
            p += __shfl_xor(p, 2);
            p += __shfl_xor(p, 4);
            p += __shfl_xor(p, 8);
            float e = expf(p);
            acc.x = fmaf(v4.x, e, acc.x);
            acc.y = fmaf(v4.y, e, acc.y);
            acc.z = fmaf(v4.z, e, acc.z);
            acc.w = fmaf(v4.w, e, acc.w);
            if ((l & 15) == 0) esum += (double)e;
        }
        ((float4*)U)[(size_t)n * 32 + l] = acc;
    }
    __shared__ double sd[2][8];
    if ((l & 15) == 0) sd[head][g] = esum;
    __syncthreads();
    if (threadIdx.x < 2) {
        double s = 0.0;
        for (int i = 0; i < 8; i++) s += sd[threadIdx.x][i];
        psum[(size_t)blockIdx.x * 2 + threadIdx.x] = s;
    }
}

// deterministic reduce of per-block partials -> sumf[2] (double)
__global__ void k_sum2(const double* __restrict__ psum, double* __restrict__ sumf, int P) {
    double s0 = 0.0, s1 = 0.0;
    for (int i = threadIdx.x; i < P; i += blockDim.x) {
        s0 += psum[2 * i];
        s1 += psum[2 * i + 1];
    }
    for (int off = 32; off; off >>= 1) {
        s0 += __shfl_xor(s0, off);
        s1 += __shfl_xor(s1, off);
    }
    __shared__ double sd[2][4];
    int w = threadIdx.x >> 6;
    if ((threadIdx.x & 63) == 0) { sd[0][w] = s0; sd[1][w] = s1; }
    __syncthreads();
    if (threadIdx.x == 0) {
        for (int i = 1; i < 4; i++) { s0 += sd[0][i]; s1 += sd[1][i]; }
        sumf[0] = s0;
        sumf[1] = s1;
    }
}

// ---------------- rows 0-3 of out + cross-ratio scale factor ----------------
__global__ void k_crout4(const float* __restrict__ U, const float* __restrict__ Wo,
                         const float* __restrict__ bo, const double* __restrict__ sumf,
                         const double* __restrict__ crinit, float* __restrict__ scalef) {
    __shared__ float xs[4 * 128];
    __shared__ float o4[4 * 64];
    int tid = threadIdx.x;  // 256
    xs[tid] = U[tid];
    xs[tid + 256] = U[tid + 256];
    __syncthreads();
    int w = tid >> 6, o = tid & 63;
    float si0 = (float)(1.0 / sumf[0]);
    float si1 = (float)(1.0 / sumf[1]);
    const float* xr = xs + w * 128;
    const float* wr = Wo + (size_t)o * 128;
    float d0 = 0.f, d1 = 0.f;
    for (int j = 0; j < 64; j++) d0 = fmaf(xr[j], wr[j], d0);
    for (int j = 64; j < 128; j++) d1 = fmaf(xr[j], wr[j], d1);
    o4[w * 64 + o] = d0 * si0 + d1 * si1 + bo[o];
    __syncthreads();
    if (tid < 64) {
        int l = tid;
        const int pa[4] = {0, 1, 0, 1};
        const int pb[4] = {2, 3, 3, 2};
        double inner[4];
        for (int p = 0; p < 4; p++) {
            double t = (double)o4[pa[p] * 64 + l] * (double)o4[pb[p] * 64 + l];
            if (l == 63) t = -t;
            for (int off = 32; off; off >>= 1) t += __shfl_xor(t, off);
            inner[p] = t;
        }
        if (l == 0) {
            double num = inner[0] * inner[1];
            double den = inner[2] * inner[3];
            if (fabs(den) < 1e-9) den = 1e-9;
            double crc = num / den;
            if (fabs(crc) < 1e-9) crc = 1e-9;
            double ratio = crinit[0] / crc;
            scalef[0] = (float)pow(fabs(ratio), 0.25);
        }
    }
}

// ---------------- final GEMM: out = ((U/sumf) @ Wo.T + bo) * scalef ----------------
// Register-tiled like k_proj: M=64, N'=64, 4x4 per lane; 1/sumf folded into
// the staged A operand (khalf boundary == head boundary), scalef in epilogue.
__global__ void __launch_bounds__(256, 2)
k_out2(const float* __restrict__ U, const float* __restrict__ Wo,
       const float* __restrict__ bo, const double* __restrict__ sumf,
       const float* __restrict__ scalef, float* __restrict__ out, int N) {
    __shared__ float4 xs4[64 * 32];   // 32 KB
    __shared__ float4 ws4[64 * 16];   // 16 KB (one K-half of Wo)
    int tid = threadIdx.x;
    int rg = tid >> 4;       // 16 row-groups x 4 rows
    int cg = tid & 15;       // 16 col-groups x 4 cols
    int base = blockIdx.x * 64;

    float si0 = (float)(1.0 / sumf[0]);
    float si1 = (float)(1.0 / sumf[1]);
    const float4* U4 = (const float4*)U;
    const float4* Wo4 = (const float4*)Wo;

#pragma unroll
    for (int i2 = 0; i2 < 8; i2++) {
        int idx = tid + i2 * 256;
        int r = idx >> 5, kc = idx & 31;
        int row = base + r;
        float4 v = {0.f, 0.f, 0.f, 0.f};
        if (row < N) {
            v = U4[(size_t)row * 32 + kc];
            float si = (kc < 16) ? si0 : si1;
            v.x *= si; v.y *= si; v.z *= si; v.w *= si;
        }
        xs4[XS2(r, kc)] = v;
    }

    float acc[4][4];
#pragma unroll
    for (int i = 0; i < 4; i++)
#pragma unroll
        for (int j = 0; j < 4; j++) acc[i][j] = 0.f;

    for (int kp = 0; kp < 2; kp++) {
        __syncthreads();
#pragma unroll
        for (int i2 = 0; i2 < 4; i2++) {
            int idx = tid + i2 * 256;
            int c = idx >> 4, kc2 = idx & 15;
            ws4[WS2(c, kc2)] = Wo4[(size_t)c * 32 + kp * 16 + kc2];
        }
        __syncthreads();
        for (int kc2 = 0; kc2 < 16; kc2++) {
            int kc = kp * 16 + kc2;
            float4 xa[4], wb[4];
#pragma unroll
            for (int i = 0; i < 4; i++) xa[i] = xs4[XS2(rg * 4 + i, kc)];
#pragma unroll
            for (int j = 0; j < 4; j++) wb[j] = ws4[WS2(cg * 4 + j, kc2)];
#pragma unroll
            for (int i = 0; i < 4; i++)
#pragma unroll
                for (int j = 0; j < 4; j++) {
                    acc[i][j] = fmaf(xa[i].x, wb[j].x, acc[i][j]);
                    acc[i][j] = fmaf(xa[i].y, wb[j].y, acc[i][j]);
                    acc[i][j] = fmaf(xa[i].z, wb[j].z, acc[i][j]);
                    acc[i][j] = fmaf(xa[i].w, wb[j].w, acc[i][j]);
                }
        }
    }

    float4 bb = ((const float4*)bo)[cg];
    float sf = scalef[0];
#pragma unroll
    for (int i = 0; i < 4; i++) {
        int row = base + rg * 4 + i;
        if (row < N) {
            float4 o;
            o.x = (acc[i][0] + bb.x) * sf;
            o.y = (acc[i][1] + bb.y) * sf;
            o.z = (acc[i][2] + bb.z) * sf;
            o.w = (acc[i][3] + bb.w) * sf;
            ((float4*)(out + (size_t)row * 64))[cg] = o;
        }
    }
}

extern "C" void kernel_launch(void* const* d_in, const int* in_sizes, int n_in,
                              void* d_out, int out_size, void* d_ws, size_t ws_size,
                              hipStream_t stream) {
    const float* x  = (const float*)d_in[0];
    const int*   ei = (const int*)d_in[1];
    const float* Wq = (const float*)d_in[2];
    const float* bq = (const float*)d_in[3];
    const float* Wk = (const float*)d_in[4];
    const float* bk = (const float*)d_in[5];
    const float* Wv = (const float*)d_in[6];
    const float* bv = (const float*)d_in[7];
    const float* Wo = (const float*)d_in[8];
    const float* bo = (const float*)d_in[9];
    float* out = (float*)d_out;

    const int N = in_sizes[0] / 128;   // 100000
    const int E = in_sizes[1] / 2;
    const size_t NR = (size_t)N * 128;
    const int NB64 = (N + 63) / 64;    // 1563 blocks for tiled GEMM kernels
    const int GB = (N + 7) / 8;        // 12500 blocks for the edge kernel

    float* qn = (float*)d_ws;          // N*128 ; reused as U after k_edge
    float* kv = qn + NR;               // N*256 (k|v interleaved per node)
    float* xp = kv + NR * 2;           // N*128 ; region reused after projections:
    int* counts = (int*)xp;                    // N
    int* offs   = counts + N;                  // N+2
    int* cursor = offs + N + 2;                // N
    int* ccol   = cursor + N;                  // E
    double* psum = (double*)(ccol + E);        // GB*2 partial expsums
    int* tsum   = (int*)(psum + (size_t)GB * 2);  // scan tiles

    double* crinit = (double*)(xp + NR);
    double* sumf   = crinit + 1;               // 2 doubles
    float* scalef  = (float*)(sumf + 2);       // 1

    float* U = qn;  // aggregation output aliases q (safe: per-n read-then-write)

    const int T = (N + 1023) / 1024;

    k_cr_init<<<1, 64, 0, stream>>>(x, crinit);
    k_normx<<<(N * 64 + 255) / 256, 256, 0, stream>>>(x, xp, N);
    k_proj<0><<<NB64, 256, 0, stream>>>(xp, Wq, bq, qn, 128, 0, N);
    k_proj<1><<<NB64, 256, 0, stream>>>(xp, Wk, bk, kv, 256, 0, N);
    k_proj<2><<<NB64, 256, 0, stream>>>(xp, Wv, bv, kv, 256, 128, N);
    hipMemsetAsync(counts, 0, (size_t)N * sizeof(int), stream);
    k_hist<<<1024, 256, 0, stream>>>(ei, counts, E);
    k_scan1<<<T, 256, 0, stream>>>(counts, offs, tsum, N);
    k_scan2<<<1, 64, 0, stream>>>(tsum, offs, T, N);
    k_scan3<<<(N + 255) / 256, 256, 0, stream>>>(offs, cursor, tsum, N);
    k_fill<<<1024, 256, 0, stream>>>(ei, cursor, ccol, E);
    k_edge<<<GB, 256, 0, stream>>>(qn, kv, offs, ccol, U, psum, N);
    k_sum2<<<1, 256, 0, stream>>>(psum, sumf, GB);
    k_crout4<<<1, 256, 0, stream>>>(U, Wo, bo, sumf, crinit, scalef);
    k_out2<<<NB64, 256, 0, stream>>>(U, Wo, bo, sumf, scalef, out, N);
}

// Round 7
// 628.609 us; speedup vs baseline: 2.8468x; 1.0205x over previous
//
#include <hip/hip_runtime.h>
#include <math.h>

#define EPSF 1e-9f
#define INV_SQRT128 0.08838834764831845f

// LDS swizzles (indices in float4 units) to spread banks at the bw floor
#define XS(r, kc)  ((r) * 32 + ((kc) ^ (((r) >> 3) & 7)))   // kc < 32
#define WSQ(c, kc) ((c) * 8  + ((kc) ^ (((c) >> 2) & 7)))   // kc < 8  (K-quarter)
#define XS2(r, kc) ((r) * 32 + ((kc) ^ (((r) >> 2) & 7)))   // kc < 32
#define WS2(c, kc) ((c) * 16 + ((kc) ^ (((c) >> 2) & 7)))   // kc < 16 (K-half)

// ---------------- fused: x-normalize + q/k/v projections (+ histogram role) ----------------
// normalize_points(x)@W.T == (x_mod @ W.T)/nm  with x_mod = x except elem127 *= nm.
// So: stage raw x tile once, fix elem 127 in LDS, divide by nm in the epilogue.
// Blocks >= NB run the CSR histogram instead (independent work, overlapped).
__global__ void __launch_bounds__(256, 2)
k_qkv3(const float* __restrict__ x,
       const float* __restrict__ Wq, const float* __restrict__ bq,
       const float* __restrict__ Wk, const float* __restrict__ bk,
       const float* __restrict__ Wv, const float* __restrict__ bv,
       float* __restrict__ qn, float* __restrict__ kvout,
       const int* __restrict__ ei, int* __restrict__ counts,
       int NB, int N, int E) {
    if ((int)blockIdx.x >= NB) {   // histogram role
        int stride = ((int)gridDim.x - NB) * 256;
        for (int e = ((int)blockIdx.x - NB) * 256 + (int)threadIdx.x; e < E; e += stride)
            atomicAdd(&counts[ei[e]], 1);
        return;
    }

    __shared__ float4 xs4[64 * 32];   // 32 KB raw-x tile (elem127 scaled by nm)
    __shared__ float4 ws4[128 * 8];   // 16 KB W K-quarter
    __shared__ float rnormS[64];
    __shared__ float pnorm[64][4];
    int tid = threadIdx.x;
    int rg = tid >> 5;       // 8 row-groups x 8 rows
    int cg = tid & 31;       // 32 col-groups x 4 cols
    int base = blockIdx.x * 64;
    const float4* x4 = (const float4*)x;

    // stage raw x tile (guarded, zeros past N)
#pragma unroll
    for (int i2 = 0; i2 < 8; i2++) {
        int idx = tid + i2 * 256;
        int r = idx >> 5, kc = idx & 31;
        int row = base + r;
        float4 v = {0.f, 0.f, 0.f, 0.f};
        if (row < N) v = x4[(size_t)row * 32 + kc];
        xs4[XS(r, kc)] = v;
    }
    __syncthreads();

    // row norms over spatial elems 0..126: 4 threads per row
    {
        int r = tid >> 2, qtr = tid & 3;
        float ss = 0.f;
#pragma unroll
        for (int k2 = 0; k2 < 8; k2++) {
            int kc = qtr * 8 + k2;
            float4 v = xs4[XS(r, kc)];
            ss += v.x * v.x + v.y * v.y + v.z * v.z + ((kc == 31) ? 0.f : v.w * v.w);
        }
        pnorm[r][qtr] = ss;
    }
    __syncthreads();
    if (tid < 64) {
        int r = tid;
        float nm = fmaxf(sqrtf(pnorm[r][0] + pnorm[r][1] + pnorm[r][2] + pnorm[r][3]), EPSF);
        rnormS[r] = 1.f / nm;
        float4 v = xs4[XS(r, 31)];
        v.w *= nm;                  // x_mod: acc/nm then yields [x_s/nm | x_t]
        xs4[XS(r, 31)] = v;
    }
    __syncthreads();

    float rinv[8];
#pragma unroll
    for (int i = 0; i < 8; i++) rinv[i] = rnormS[rg * 8 + i];

    const float* const Wks[3] = {Wq, Wk, Wv};
    const float* const bks[3] = {bq, bk, bv};
    bool istime = ((cg & 15) == 15);  // col cg*4+3 is this head's time coord

#pragma unroll
    for (int kind = 0; kind < 3; kind++) {
        const float4* W4 = (const float4*)Wks[kind];
        float acc[8][4];
#pragma unroll
        for (int i = 0; i < 8; i++)
#pragma unroll
            for (int j = 0; j < 4; j++) acc[i][j] = 0.f;

        for (int kp = 0; kp < 4; kp++) {
            __syncthreads();
#pragma unroll
            for (int i2 = 0; i2 < 4; i2++) {
                int idx = tid + i2 * 256;
                int c = idx >> 3, kc2 = idx & 7;
                ws4[WSQ(c, kc2)] = W4[(size_t)c * 32 + kp * 8 + kc2];
            }
            __syncthreads();
            for (int kc2 = 0; kc2 < 8; kc2++) {
                int kc = kp * 8 + kc2;
                float4 xa[8], wb[4];
#pragma unroll
                for (int i = 0; i < 8; i++) xa[i] = xs4[XS(rg * 8 + i, kc)];
#pragma unroll
                for (int j = 0; j < 4; j++) wb[j] = ws4[WSQ(cg * 4 + j, kc2)];
#pragma unroll
                for (int i = 0; i < 8; i++)
#pragma unroll
                    for (int j = 0; j < 4; j++) {
                        acc[i][j] = fmaf(xa[i].x, wb[j].x, acc[i][j]);
                        acc[i][j] = fmaf(xa[i].y, wb[j].y, acc[i][j]);
                        acc[i][j] = fmaf(xa[i].z, wb[j].z, acc[i][j]);
                        acc[i][j] = fmaf(xa[i].w, wb[j].w, acc[i][j]);
                    }
            }
        }

        // epilogue: /nm, +bias, per-(row,head) normalize for q/k
        float4 bb = ((const float4*)bks[kind])[cg];
#pragma unroll
        for (int i = 0; i < 8; i++) {
            int row = base + rg * 8 + i;
            float v0 = acc[i][0] * rinv[i] + bb.x;
            float v1 = acc[i][1] * rinv[i] + bb.y;
            float v2 = acc[i][2] * rinv[i] + bb.z;
            float v3 = acc[i][3] * rinv[i] + bb.w;
            if (kind < 2) {
                float ss = v0 * v0 + v1 * v1 + v2 * v2 + (istime ? 0.f : v3 * v3);
                ss += __shfl_xor(ss, 1);
                ss += __shfl_xor(ss, 2);
                ss += __shfl_xor(ss, 4);
                ss += __shfl_xor(ss, 8);
                float rn = 1.f / fmaxf(sqrtf(ss), EPSF);
                v0 *= rn; v1 *= rn; v2 *= rn;
                if (!istime) v3 *= rn;
                if (kind == 0) {
                    if (istime) v3 = -v3;       // fold uhg minus into q
                    v0 *= INV_SQRT128; v1 *= INV_SQRT128;
                    v2 *= INV_SQRT128; v3 *= INV_SQRT128;
                }
            }
            if (row < N) {
                float4 o = {v0, v1, v2, v3};
                if (kind == 0)
                    ((float4*)(qn + (size_t)row * 128))[cg] = o;
                else
                    ((float4*)(kvout + (size_t)row * 256 + (kind == 2 ? 128 : 0)))[cg] = o;
            }
        }
    }
}

// ---------------- CSR build (scan + fill) ----------------
__global__ void k_scan1(const int* __restrict__ counts, int* __restrict__ offs,
                        int* __restrict__ tsum, int N) {
    __shared__ int sd[256];
    int tile = blockIdx.x;
    int t = threadIdx.x;
    int i0 = tile * 1024 + t * 4;
    int v[4];
    int lsum = 0;
    for (int j = 0; j < 4; j++) {
        int idx = i0 + j;
        v[j] = (idx < N) ? counts[idx] : 0;
        lsum += v[j];
    }
    sd[t] = lsum;
    __syncthreads();
    for (int off = 1; off < 256; off <<= 1) {
        int val = sd[t];
        int add = (t >= off) ? sd[t - off] : 0;
        __syncthreads();
        sd[t] = val + add;
        __syncthreads();
    }
    int excl = (t == 0) ? 0 : sd[t - 1];
    if (t == 255) tsum[tile] = sd[255];
    int run = excl;
    for (int j = 0; j < 4; j++) {
        int idx = i0 + j;
        if (idx < N) offs[idx] = run;
        run += v[j];
    }
}

__global__ void k_scan2(int* __restrict__ tsum, int* __restrict__ offs, int T, int N) {
    if (threadIdx.x == 0) {
        int run = 0;
        for (int i = 0; i < T; i++) {
            int t = tsum[i];
            tsum[i] = run;
            run += t;
        }
        offs[N] = run;
    }
}

__global__ void k_scan3(int* __restrict__ offs, int* __restrict__ cursor,
                        const int* __restrict__ tsum, int N) {
    int i = blockIdx.x * blockDim.x + threadIdx.x;
    if (i < N) {
        int o = offs[i] + tsum[i >> 10];
        offs[i] = o;
        cursor[i] = o;
    }
}

// stores the COLUMN id in CSR order
__global__ void k_fill(const int* __restrict__ ei, int* __restrict__ cursor,
                       int* __restrict__ ccol, int E) {
    int stride = blockDim.x * gridDim.x;
    for (int e = blockIdx.x * blockDim.x + threadIdx.x; e < E; e += stride) {
        int r = ei[e];
        int p = atomicAdd(&cursor[r], 1);
        ccol[p] = ei[E + e];
    }
}

// ---------------- fused edge pass: scores + exp + aggregate (unnormalized) ----------------
// kv[n] = [k-row | v-row] (256B-local gather per edge). Unroll-2: two independent
// gather+shuffle chains in flight (round-6: VALUBusy 24%, ~50% latency-bound).
__global__ void k_edge(const float* __restrict__ qn, const float* __restrict__ kv,
                       const int* __restrict__ offs, const int* __restrict__ ccol,
                       float* __restrict__ U, double* __restrict__ psum, int N) {
    int g = threadIdx.x >> 5;            // 8 groups of 32 lanes
    int l = threadIdx.x & 31;
    int head = l >> 4;
    int n = blockIdx.x * 8 + g;
    double esum = 0.0;
    if (n < N) {
        float4 q4 = ((const float4*)qn)[(size_t)n * 32 + l];
        int s0 = offs[n], s1 = offs[n + 1];
        float4 acc = {0.f, 0.f, 0.f, 0.f};
        const float4* kv4 = (const float4*)kv;
        int i = s0;
        for (; i + 2 <= s1; i += 2) {
            int c0 = ccol[i];
            int c1 = ccol[i + 1];
            float4 ka = kv4[(size_t)c0 * 64 + l];
            float4 kb = kv4[(size_t)c1 * 64 + l];
            float4 va = kv4[(size_t)c0 * 64 + 32 + l];
            float4 vb = kv4[(size_t)c1 * 64 + 32 + l];
            float p0 = q4.x * ka.x;
            p0 = fmaf(q4.y, ka.y, p0);
            p0 = fmaf(q4.z, ka.z, p0);
            p0 = fmaf(q4.w, ka.w, p0);
            float p1 = q4.x * kb.x;
            p1 = fmaf(q4.y, kb.y, p1);
            p1 = fmaf(q4.z, kb.z, p1);
            p1 = fmaf(q4.w, kb.w, p1);
            p0 += __shfl_xor(p0, 1);
            p1 += __shfl_xor(p1, 1);
            p0 += __shfl_xor(p0, 2);
            p1 += __shfl_xor(p1, 2);
            p0 += __shfl_xor(p0, 4);
            p1 += __shfl_xor(p1, 4);
            p0 += __shfl_xor(p0, 8);
            p1 += __shfl_xor(p1, 8);
            float e0 = expf(p0);
            float e1 = expf(p1);
            acc.x = fmaf(va.x, e0, acc.x);
            acc.y = fmaf(va.y, e0, acc.y);
            acc.z = fmaf(va.z, e0, acc.z);
            acc.w = fmaf(va.w, e0, acc.w);
            acc.x = fmaf(vb.x, e1, acc.x);
            acc.y = fmaf(vb.y, e1, acc.y);
            acc.z = fmaf(vb.z, e1, acc.z);
            acc.w = fmaf(vb.w, e1, acc.w);
            if ((l & 15) == 0) esum += (double)e0 + (double)e1;
        }
        if (i < s1) {
            int c = ccol[i];
            float4 k4 = kv4[(size_t)c * 64 + l];
            float4 v4 = kv4[(size_t)c * 64 + 32 + l];
            float p = q4.x * k4.x;
            p = fmaf(q4.y, k4.y, p);
            p = fmaf(q4.z, k4.z, p);
            p = fmaf(q4.w, k4.w, p);
            p += __shfl_xor(p, 1);
            p += __shfl_xor(p, 2);
            p += __shfl_xor(p, 4);
            p += __shfl_xor(p, 8);
            float e = expf(p);
            acc.x = fmaf(v4.x, e, acc.x);
            acc.y = fmaf(v4.y, e, acc.y);
            acc.z = fmaf(v4.z, e, acc.z);
            acc.w = fmaf(v4.w, e, acc.w);
            if ((l & 15) == 0) esum += (double)e;
        }
        ((float4*)U)[(size_t)n * 32 + l] = acc;
    }
    __shared__ double sd[2][8];
    if ((l & 15) == 0) sd[head][g] = esum;
    __syncthreads();
    if (threadIdx.x < 2) {
        double s = 0.0;
        for (int i2 = 0; i2 < 8; i2++) s += sd[threadIdx.x][i2];
        psum[(size_t)blockIdx.x * 2 + threadIdx.x] = s;
    }
}

// deterministic reduce of per-block partials -> sumf[2] (double)
__global__ void k_sum2(const double* __restrict__ psum, double* __restrict__ sumf, int P) {
    double s0 = 0.0, s1 = 0.0;
    for (int i = threadIdx.x; i < P; i += blockDim.x) {
        s0 += psum[2 * i];
        s1 += psum[2 * i + 1];
    }
    for (int off = 32; off; off >>= 1) {
        s0 += __shfl_xor(s0, off);
        s1 += __shfl_xor(s1, off);
    }
    __shared__ double sd[2][4];
    int w = threadIdx.x >> 6;
    if ((threadIdx.x & 63) == 0) { sd[0][w] = s0; sd[1][w] = s1; }
    __syncthreads();
    if (threadIdx.x == 0) {
        for (int i = 1; i < 4; i++) { s0 += sd[0][i]; s1 += sd[1][i]; }
        sumf[0] = s0;
        sumf[1] = s1;
    }
}

// ---------------- cr_initial (from x) + rows 0-3 of out + scale factor ----------------
__global__ void k_crout4(const float* __restrict__ x, const float* __restrict__ U,
                         const float* __restrict__ Wo, const float* __restrict__ bo,
                         const double* __restrict__ sumf, float* __restrict__ scalef) {
    __shared__ float xs[4 * 128];
    __shared__ float o4[4 * 64];
    __shared__ double crin_sh;
    int tid = threadIdx.x;  // 256
    xs[tid] = U[tid];
    xs[tid + 256] = U[tid + 256];
    if (tid < 64) {         // wave 0: cross-ratio of raw x rows 0..3
        int l = tid;
        const int pa[4] = {0, 1, 0, 1};
        const int pb[4] = {2, 3, 3, 2};
        double inner[4];
        for (int p = 0; p < 4; p++) {
            const float* a = x + pa[p] * 128;
            const float* b = x + pb[p] * 128;
            double s = (double)a[l] * (double)b[l];
            double t = (double)a[l + 64] * (double)b[l + 64];
            s += (l == 63) ? -t : t;
            for (int off = 32; off; off >>= 1) s += __shfl_xor(s, off);
            inner[p] = s;
        }
        if (l == 0) {
            double num = inner[0] * inner[1];
            double den = inner[2] * inner[3];
            if (fabs(den) < 1e-9) den = 1e-9;
            crin_sh = num / den;
        }
    }
    __syncthreads();
    int w = tid >> 6, o = tid & 63;
    float si0 = (float)(1.0 / sumf[0]);
    float si1 = (float)(1.0 / sumf[1]);
    const float* xr = xs + w * 128;
    const float* wr = Wo + (size_t)o * 128;
    float d0 = 0.f, d1 = 0.f;
    for (int j = 0; j < 64; j++) d0 = fmaf(xr[j], wr[j], d0);
    for (int j = 64; j < 128; j++) d1 = fmaf(xr[j], wr[j], d1);
    o4[w * 64 + o] = d0 * si0 + d1 * si1 + bo[o];
    __syncthreads();
    if (tid < 64) {
        int l = tid;
        const int pa[4] = {0, 1, 0, 1};
        const int pb[4] = {2, 3, 3, 2};
        double inner[4];
        for (int p = 0; p < 4; p++) {
            double t = (double)o4[pa[p] * 64 + l] * (double)o4[pb[p] * 64 + l];
            if (l == 63) t = -t;
            for (int off = 32; off; off >>= 1) t += __shfl_xor(t, off);
            inner[p] = t;
        }
        if (l == 0) {
            double num = inner[0] * inner[1];
            double den = inner[2] * inner[3];
            if (fabs(den) < 1e-9) den = 1e-9;
            double crc = num / den;
            if (fabs(crc) < 1e-9) crc = 1e-9;
            double ratio = crin_sh / crc;
            scalef[0] = (float)pow(fabs(ratio), 0.25);
        }
    }
}

// ---------------- final GEMM: out = ((U/sumf) @ Wo.T + bo) * scalef ----------------
__global__ void __launch_bounds__(256, 2)
k_out2(const float* __restrict__ U, const float* __restrict__ Wo,
       const float* __restrict__ bo, const double* __restrict__ sumf,
       const float* __restrict__ scalef, float* __restrict__ out, int N) {
    __shared__ float4 xs4[64 * 32];   // 32 KB
    __shared__ float4 ws4[64 * 16];   // 16 KB (one K-half of Wo)
    int tid = threadIdx.x;
    int rg = tid >> 4;       // 16 row-groups x 4 rows
    int cg = tid & 15;       // 16 col-groups x 4 cols
    int base = blockIdx.x * 64;

    float si0 = (float)(1.0 / sumf[0]);
    float si1 = (float)(1.0 / sumf[1]);
    const float4* U4 = (const float4*)U;
    const float4* Wo4 = (const float4*)Wo;

#pragma unroll
    for (int i2 = 0; i2 < 8; i2++) {
        int idx = tid + i2 * 256;
        int r = idx >> 5, kc = idx & 31;
        int row = base + r;
        float4 v = {0.f, 0.f, 0.f, 0.f};
        if (row < N) {
            v = U4[(size_t)row * 32 + kc];
            float si = (kc < 16) ? si0 : si1;
            v.x *= si; v.y *= si; v.z *= si; v.w *= si;
        }
        xs4[XS2(r, kc)] = v;
    }

    float acc[4][4];
#pragma unroll
    for (int i = 0; i < 4; i++)
#pragma unroll
        for (int j = 0; j < 4; j++) acc[i][j] = 0.f;

    for (int kp = 0; kp < 2; kp++) {
        __syncthreads();
#pragma unroll
        for (int i2 = 0; i2 < 4; i2++) {
            int idx = tid + i2 * 256;
            int c = idx >> 4, kc2 = idx & 15;
            ws4[WS2(c, kc2)] = Wo4[(size_t)c * 32 + kp * 16 + kc2];
        }
        __syncthreads();
        for (int kc2 = 0; kc2 < 16; kc2++) {
            int kc = kp * 16 + kc2;
            float4 xa[4], wb[4];
#pragma unroll
            for (int i = 0; i < 4; i++) xa[i] = xs4[XS2(rg * 4 + i, kc)];
#pragma unroll
            for (int j = 0; j < 4; j++) wb[j] = ws4[WS2(cg * 4 + j, kc2)];
#pragma unroll
            for (int i = 0; i < 4; i++)
#pragma unroll
                for (int j = 0; j < 4; j++) {
                    acc[i][j] = fmaf(xa[i].x, wb[j].x, acc[i][j]);
                    acc[i][j] = fmaf(xa[i].y, wb[j].y, acc[i][j]);
                    acc[i][j] = fmaf(xa[i].z, wb[j].z, acc[i][j]);
                    acc[i][j] = fmaf(xa[i].w, wb[j].w, acc[i][j]);
                }
        }
    }

    float4 bb = ((const float4*)bo)[cg];
    float sf = scalef[0];
#pragma unroll
    for (int i = 0; i < 4; i++) {
        int row = base + rg * 4 + i;
        if (row < N) {
            float4 o;
            o.x = (acc[i][0] + bb.x) * sf;
            o.y = (acc[i][1] + bb.y) * sf;
            o.z = (acc[i][2] + bb.z) * sf;
            o.w = (acc[i][3] + bb.w) * sf;
            ((float4*)(out + (size_t)row * 64))[cg] = o;
        }
    }
}

extern "C" void kernel_launch(void* const* d_in, const int* in_sizes, int n_in,
                              void* d_out, int out_size, void* d_ws, size_t ws_size,
                              hipStream_t stream) {
    const float* x  = (const float*)d_in[0];
    const int*   ei = (const int*)d_in[1];
    const float* Wq = (const float*)d_in[2];
    const float* bq = (const float*)d_in[3];
    const float* Wk = (const float*)d_in[4];
    const float* bk = (const float*)d_in[5];
    const float* Wv = (const float*)d_in[6];
    const float* bv = (const float*)d_in[7];
    const float* Wo = (const float*)d_in[8];
    const float* bo = (const float*)d_in[9];
    float* out = (float*)d_out;

    const int N = in_sizes[0] / 128;   // 100000
    const int E = in_sizes[1] / 2;
    const size_t NR = (size_t)N * 128;
    const int NB64 = (N + 63) / 64;    // 1563 tiled-GEMM blocks
    const int HB = 512;                // histogram-role blocks appended to k_qkv3
    const int GB = (N + 7) / 8;        // 12500 edge-kernel blocks
    const int T = (N + 1023) / 1024;

    float* qn = (float*)d_ws;          // N*128 ; reused as U after k_edge
    float* kv = qn + NR;               // N*256 (k|v interleaved per node)
    int* counts = (int*)(kv + NR * 2);         // N
    int* offs   = counts + N;                  // N+2
    int* cursor = offs + N + 2;                // N
    int* ccol   = cursor + N;                  // E
    double* psum = (double*)(ccol + E);        // GB*2 partial expsums
    int* tsum   = (int*)(psum + (size_t)GB * 2);  // T scan tiles
    double* sumf = (double*)(tsum + T + (T & 1)); // 2 doubles (8B aligned)
    float* scalef = (float*)(sumf + 2);           // 1

    float* U = qn;  // aggregation output aliases q (per-n read-then-write)

    hipMemsetAsync(counts, 0, (size_t)N * sizeof(int), stream);
    k_qkv3<<<NB64 + HB, 256, 0, stream>>>(x, Wq, bq, Wk, bk, Wv, bv,
                                          qn, kv, ei, counts, NB64, N, E);
    k_scan1<<<T, 256, 0, stream>>>(counts, offs, tsum, N);
    k_scan2<<<1, 64, 0, stream>>>(tsum, offs, T, N);
    k_scan3<<<(N + 255) / 256, 256, 0, stream>>>(offs, cursor, tsum, N);
    k_fill<<<1024, 256, 0, stream>>>(ei, cursor, ccol, E);
    k_edge<<<GB, 256, 0, stream>>>(qn, kv, offs, ccol, U, psum, N);
    k_sum2<<<1, 256, 0, stream>>>(psum, sumf, GB);
    k_crout4<<<1, 256, 0, stream>>>(x, U, Wo, bo, sumf, scalef);
    k_out2<<<NB64, 256, 0, stream>>>(U, Wo, bo, sumf, scalef, out, N);
}

// Round 8
// 598.921 us; speedup vs baseline: 2.9879x; 1.0496x over previous
//
#include <hip/hip_runtime.h>
#include <math.h>

#define EPSF 1e-9f
#define INV_SQRT128 0.08838834764831845f

// LDS swizzles (indices in float4 units)
#define XS(r, kc)  ((r) * 32 + ((kc) ^ (((r) >> 3) & 7)))   // kc < 32
#define WSQ(c, kc) ((c) * 8  + ((kc) ^ (((c) >> 3) & 7)))   // kc < 8  (K-quarter, 8x8 kernel)
#define XS2(r, kc) ((r) * 32 + ((kc) ^ (((r) >> 2) & 7)))   // kc < 32
#define WS2(c, kc) ((c) * 16 + ((kc) ^ (((c) >> 2) & 7)))   // kc < 16 (K-half)

// ---------------- fused: x-normalize + q/k/v projections (+ histogram role) ----------------
// 128 threads/block, 64 rows, 8x8 register tile (B/MAC = 1.0; round-7's 256-thr
// 8x4 tile was LDS-return-bound at 1.5 B/MAC). Row norms computed from staging
// REGISTERS via 32-lane shfl_xor butterfly -- round 7's LDS norm phase hit 8-way
// bank conflicts (SQ_LDS_BANK_CONFLICT 1.1e7) and is gone entirely; the LDS tile
// holds normalize(x) directly (spatial/nm, elem127 raw).
// Blocks >= NB run the CSR histogram instead (independent work, overlapped).
__global__ void __launch_bounds__(128, 2)
k_qkv3(const float* __restrict__ x,
       const float* __restrict__ Wq, const float* __restrict__ bq,
       const float* __restrict__ Wk, const float* __restrict__ bk,
       const float* __restrict__ Wv, const float* __restrict__ bv,
       float* __restrict__ qn, float* __restrict__ kvout,
       const int* __restrict__ ei, int* __restrict__ counts,
       int NB, int N, int E) {
    if ((int)blockIdx.x >= NB) {   // histogram role
        int stride = ((int)gridDim.x - NB) * 128;
        for (int e = ((int)blockIdx.x - NB) * 128 + (int)threadIdx.x; e < E; e += stride)
            atomicAdd(&counts[ei[e]], 1);
        return;
    }

    __shared__ float4 xs4[64 * 32];   // 32 KB normalized-x tile
    __shared__ float4 ws4[128 * 8];   // 16 KB W K-quarter
    int tid = threadIdx.x;            // 0..127
    int rg = tid >> 4;                // 8 row-groups x 8 rows
    int cg = tid & 15;                // 16 col-groups x 8 cols
    int base = blockIdx.x * 64;
    const float4* x4 = (const float4*)x;

    // stage raw x into registers; per-row |spatial|^2 partials alongside.
    // thread holds rows (tid>>5)+4*i2, all at kc = tid&31.
    float4 v[16];
    float ssl[16];
#pragma unroll
    for (int i2 = 0; i2 < 16; i2++) {
        int idx = tid + i2 * 128;
        int r = idx >> 5, kc = idx & 31;
        int row = base + r;
        float4 t = {0.f, 0.f, 0.f, 0.f};
        if (row < N) t = x4[(size_t)row * 32 + kc];
        v[i2] = t;
        ssl[i2] = t.x * t.x + t.y * t.y + t.z * t.z + ((kc == 31) ? 0.f : t.w * t.w);
    }
    // butterfly over the 32-lane group (lanes share tid>>5) -> all lanes get row sums
#pragma unroll
    for (int i2 = 0; i2 < 16; i2++) {
        float s = ssl[i2];
        s += __shfl_xor(s, 1);
        s += __shfl_xor(s, 2);
        s += __shfl_xor(s, 4);
        s += __shfl_xor(s, 8);
        s += __shfl_xor(s, 16);
        ssl[i2] = s;
    }
    // scale (normalize) in registers, store swizzled
#pragma unroll
    for (int i2 = 0; i2 < 16; i2++) {
        int idx = tid + i2 * 128;
        int r = idx >> 5, kc = idx & 31;
        float rn = 1.f / fmaxf(sqrtf(ssl[i2]), EPSF);
        float4 t = v[i2];
        t.x *= rn; t.y *= rn; t.z *= rn;
        if (kc != 31) t.w *= rn;          // elem 127 (time) stays raw
        xs4[XS(r, kc)] = t;
    }
    __syncthreads();

    const float* const Wks[3] = {Wq, Wk, Wv};
    const float* const bks[3] = {bq, bk, bv};
    bool istime = ((cg & 7) == 7);        // col cg*8+7 is this head's time coord

#pragma unroll
    for (int kind = 0; kind < 3; kind++) {
        const float4* W4 = (const float4*)Wks[kind];
        float acc[8][8];
#pragma unroll
        for (int i = 0; i < 8; i++)
#pragma unroll
            for (int j = 0; j < 8; j++) acc[i][j] = 0.f;

        for (int kp = 0; kp < 4; kp++) {
            __syncthreads();
#pragma unroll
            for (int i2 = 0; i2 < 8; i2++) {
                int idx = tid + i2 * 128;
                int c = idx >> 3, kc2 = idx & 7;
                ws4[WSQ(c, kc2)] = W4[(size_t)c * 32 + kp * 8 + kc2];
            }
            __syncthreads();
            for (int kc2 = 0; kc2 < 8; kc2++) {
                int kc = kp * 8 + kc2;
                float4 xa[8], wb[8];
#pragma unroll
                for (int i = 0; i < 8; i++) xa[i] = xs4[XS(rg * 8 + i, kc)];
#pragma unroll
                for (int j = 0; j < 8; j++) wb[j] = ws4[WSQ(cg * 8 + j, kc2)];
#pragma unroll
                for (int i = 0; i < 8; i++)
#pragma unroll
                    for (int j = 0; j < 8; j++) {
                        acc[i][j] = fmaf(xa[i].x, wb[j].x, acc[i][j]);
                        acc[i][j] = fmaf(xa[i].y, wb[j].y, acc[i][j]);
                        acc[i][j] = fmaf(xa[i].z, wb[j].z, acc[i][j]);
                        acc[i][j] = fmaf(xa[i].w, wb[j].w, acc[i][j]);
                    }
            }
        }

        // epilogue: +bias, per-(row,head) normalize for q/k, store 2 float4/row
        float4 bb0 = ((const float4*)bks[kind])[cg * 2];
        float4 bb1 = ((const float4*)bks[kind])[cg * 2 + 1];
#pragma unroll
        for (int i = 0; i < 8; i++) {
            int row = base + rg * 8 + i;
            float c0 = acc[i][0] + bb0.x;
            float c1 = acc[i][1] + bb0.y;
            float c2 = acc[i][2] + bb0.z;
            float c3 = acc[i][3] + bb0.w;
            float c4 = acc[i][4] + bb1.x;
            float c5 = acc[i][5] + bb1.y;
            float c6 = acc[i][6] + bb1.z;
            float c7 = acc[i][7] + bb1.w;
            if (kind < 2) {
                float ss = c0 * c0 + c1 * c1 + c2 * c2 + c3 * c3 +
                           c4 * c4 + c5 * c5 + c6 * c6 + (istime ? 0.f : c7 * c7);
                // head = 8 consecutive lanes (same rg); sum over cg&7
                ss += __shfl_xor(ss, 1);
                ss += __shfl_xor(ss, 2);
                ss += __shfl_xor(ss, 4);
                float rn = 1.f / fmaxf(sqrtf(ss), EPSF);
                c0 *= rn; c1 *= rn; c2 *= rn; c3 *= rn;
                c4 *= rn; c5 *= rn; c6 *= rn;
                if (!istime) c7 *= rn;
                if (kind == 0) {
                    if (istime) c7 = -c7;       // fold uhg minus into q
                    c0 *= INV_SQRT128; c1 *= INV_SQRT128;
                    c2 *= INV_SQRT128; c3 *= INV_SQRT128;
                    c4 *= INV_SQRT128; c5 *= INV_SQRT128;
                    c6 *= INV_SQRT128; c7 *= INV_SQRT128;
                }
            }
            if (row < N) {
                float4 o0 = {c0, c1, c2, c3};
                float4 o1 = {c4, c5, c6, c7};
                float4* dst = (kind == 0)
                    ? (float4*)(qn + (size_t)row * 128)
                    : (float4*)(kvout + (size_t)row * 256 + (kind == 2 ? 128 : 0));
                dst[cg * 2] = o0;
                dst[cg * 2 + 1] = o1;
            }
        }
    }
}

// ---------------- CSR build (scan + fill) ----------------
__global__ void k_scan1(const int* __restrict__ counts, int* __restrict__ offs,
                        int* __restrict__ tsum, int N) {
    __shared__ int sd[256];
    int tile = blockIdx.x;
    int t = threadIdx.x;
    int i0 = tile * 1024 + t * 4;
    int v[4];
    int lsum = 0;
    for (int j = 0; j < 4; j++) {
        int idx = i0 + j;
        v[j] = (idx < N) ? counts[idx] : 0;
        lsum += v[j];
    }
    sd[t] = lsum;
    __syncthreads();
    for (int off = 1; off < 256; off <<= 1) {
        int val = sd[t];
        int add = (t >= off) ? sd[t - off] : 0;
        __syncthreads();
        sd[t] = val + add;
        __syncthreads();
    }
    int excl = (t == 0) ? 0 : sd[t - 1];
    if (t == 255) tsum[tile] = sd[255];
    int run = excl;
    for (int j = 0; j < 4; j++) {
        int idx = i0 + j;
        if (idx < N) offs[idx] = run;
        run += v[j];
    }
}

__global__ void k_scan2(int* __restrict__ tsum, int* __restrict__ offs, int T, int N) {
    if (threadIdx.x == 0) {
        int run = 0;
        for (int i = 0; i < T; i++) {
            int t = tsum[i];
            tsum[i] = run;
            run += t;
        }
        offs[N] = run;
    }
}

__global__ void k_scan3(int* __restrict__ offs, int* __restrict__ cursor,
                        const int* __restrict__ tsum, int N) {
    int i = blockIdx.x * blockDim.x + threadIdx.x;
    if (i < N) {
        int o = offs[i] + tsum[i >> 10];
        offs[i] = o;
        cursor[i] = o;
    }
}

// stores the COLUMN id in CSR order
__global__ void k_fill(const int* __restrict__ ei, int* __restrict__ cursor,
                       int* __restrict__ ccol, int E) {
    int stride = blockDim.x * gridDim.x;
    for (int e = blockIdx.x * blockDim.x + threadIdx.x; e < E; e += stride) {
        int r = ei[e];
        int p = atomicAdd(&cursor[r], 1);
        ccol[p] = ei[E + e];
    }
}

// ---------------- fused edge pass: scores + exp + aggregate (unnormalized) ----------------
// kv[n] = [k-row | v-row] (256B-local gather per edge). Unroll-2 for MLP.
__global__ void k_edge(const float* __restrict__ qn, const float* __restrict__ kv,
                       const int* __restrict__ offs, const int* __restrict__ ccol,
                       float* __restrict__ U, double* __restrict__ psum, int N) {
    int g = threadIdx.x >> 5;            // 8 groups of 32 lanes
    int l = threadIdx.x & 31;
    int head = l >> 4;
    int n = blockIdx.x * 8 + g;
    double esum = 0.0;
    if (n < N) {
        float4 q4 = ((const float4*)qn)[(size_t)n * 32 + l];
        int s0 = offs[n], s1 = offs[n + 1];
        float4 acc = {0.f, 0.f, 0.f, 0.f};
        const float4* kv4 = (const float4*)kv;
        int i = s0;
        for (; i + 2 <= s1; i += 2) {
            int c0 = ccol[i];
            int c1 = ccol[i + 1];
            float4 ka = kv4[(size_t)c0 * 64 + l];
            float4 kb = kv4[(size_t)c1 * 64 + l];
            float4 va = kv4[(size_t)c0 * 64 + 32 + l];
            float4 vb = kv4[(size_t)c1 * 64 + 32 + l];
            float p0 = q4.x * ka.x;
            p0 = fmaf(q4.y, ka.y, p0);
            p0 = fmaf(q4.z, ka.z, p0);
            p0 = fmaf(q4.w, ka.w, p0);
            float p1 = q4.x * kb.x;
            p1 = fmaf(q4.y, kb.y, p1);
            p1 = fmaf(q4.z, kb.z, p1);
            p1 = fmaf(q4.w, kb.w, p1);
            p0 += __shfl_xor(p0, 1);
            p1 += __shfl_xor(p1, 1);
            p0 += __shfl_xor(p0, 2);
            p1 += __shfl_xor(p1, 2);
            p0 += __shfl_xor(p0, 4);
            p1 += __shfl_xor(p1, 4);
            p0 += __shfl_xor(p0, 8);
            p1 += __shfl_xor(p1, 8);
            float e0 = expf(p0);
            float e1 = expf(p1);
            acc.x = fmaf(va.x, e0, acc.x);
            acc.y = fmaf(va.y, e0, acc.y);
            acc.z = fmaf(va.z, e0, acc.z);
            acc.w = fmaf(va.w, e0, acc.w);
            acc.x = fmaf(vb.x, e1, acc.x);
            acc.y = fmaf(vb.y, e1, acc.y);
            acc.z = fmaf(vb.z, e1, acc.z);
            acc.w = fmaf(vb.w, e1, acc.w);
            if ((l & 15) == 0) esum += (double)e0 + (double)e1;
        }
        if (i < s1) {
            int c = ccol[i];
            float4 k4 = kv4[(size_t)c * 64 + l];
            float4 v4 = kv4[(size_t)c * 64 + 32 + l];
            float p = q4.x * k4.x;
            p = fmaf(q4.y, k4.y, p);
            p = fmaf(q4.z, k4.z, p);
            p = fmaf(q4.w, k4.w, p);
            p += __shfl_xor(p, 1);
            p += __shfl_xor(p, 2);
            p += __shfl_xor(p, 4);
            p += __shfl_xor(p, 8);
            float e = expf(p);
            acc.x = fmaf(v4.x, e, acc.x);
            acc.y = fmaf(v4.y, e, acc.y);
            acc.z = fmaf(v4.z, e, acc.z);
            acc.w = fmaf(v4.w, e, acc.w);
            if ((l & 15) == 0) esum += (double)e;
        }
        ((float4*)U)[(size_t)n * 32 + l] = acc;
    }
    __shared__ double sd[2][8];
    if ((l & 15) == 0) sd[head][g] = esum;
    __syncthreads();
    if (threadIdx.x < 2) {
        double s = 0.0;
        for (int i2 = 0; i2 < 8; i2++) s += sd[threadIdx.x][i2];
        psum[(size_t)blockIdx.x * 2 + threadIdx.x] = s;
    }
}

// deterministic reduce of per-block partials -> sumf[2] (double)
__global__ void k_sum2(const double* __restrict__ psum, double* __restrict__ sumf, int P) {
    double s0 = 0.0, s1 = 0.0;
    for (int i = threadIdx.x; i < P; i += blockDim.x) {
        s0 += psum[2 * i];
        s1 += psum[2 * i + 1];
    }
    for (int off = 32; off; off >>= 1) {
        s0 += __shfl_xor(s0, off);
        s1 += __shfl_xor(s1, off);
    }
    __shared__ double sd[2][4];
    int w = threadIdx.x >> 6;
    if ((threadIdx.x & 63) == 0) { sd[0][w] = s0; sd[1][w] = s1; }
    __syncthreads();
    if (threadIdx.x == 0) {
        for (int i = 1; i < 4; i++) { s0 += sd[0][i]; s1 += sd[1][i]; }
        sumf[0] = s0;
        sumf[1] = s1;
    }
}

// ---------------- cr_initial (from x) + rows 0-3 of out + scale factor ----------------
__global__ void k_crout4(const float* __restrict__ x, const float* __restrict__ U,
                         const float* __restrict__ Wo, const float* __restrict__ bo,
                         const double* __restrict__ sumf, float* __restrict__ scalef) {
    __shared__ float xs[4 * 128];
    __shared__ float o4[4 * 64];
    __shared__ double crin_sh;
    int tid = threadIdx.x;  // 256
    xs[tid] = U[tid];
    xs[tid + 256] = U[tid + 256];
    if (tid < 64) {         // wave 0: cross-ratio of raw x rows 0..3
        int l = tid;
        const int pa[4] = {0, 1, 0, 1};
        const int pb[4] = {2, 3, 3, 2};
        double inner[4];
        for (int p = 0; p < 4; p++) {
            const float* a = x + pa[p] * 128;
            const float* b = x + pb[p] * 128;
            double s = (double)a[l] * (double)b[l];
            double t = (double)a[l + 64] * (double)b[l + 64];
            s += (l == 63) ? -t : t;
            for (int off = 32; off; off >>= 1) s += __shfl_xor(s, off);
            inner[p] = s;
        }
        if (l == 0) {
            double num = inner[0] * inner[1];
            double den = inner[2] * inner[3];
            if (fabs(den) < 1e-9) den = 1e-9;
            crin_sh = num / den;
        }
    }
    __syncthreads();
    int w = tid >> 6, o = tid & 63;
    float si0 = (float)(1.0 / sumf[0]);
    float si1 = (float)(1.0 / sumf[1]);
    const float* xr = xs + w * 128;
    const float* wr = Wo + (size_t)o * 128;
    float d0 = 0.f, d1 = 0.f;
    for (int j = 0; j < 64; j++) d0 = fmaf(xr[j], wr[j], d0);
    for (int j = 64; j < 128; j++) d1 = fmaf(xr[j], wr[j], d1);
    o4[w * 64 + o] = d0 * si0 + d1 * si1 + bo[o];
    __syncthreads();
    if (tid < 64) {
        int l = tid;
        const int pa[4] = {0, 1, 0, 1};
        const int pb[4] = {2, 3, 3, 2};
        double inner[4];
        for (int p = 0; p < 4; p++) {
            double t = (double)o4[pa[p] * 64 + l] * (double)o4[pb[p] * 64 + l];
            if (l == 63) t = -t;
            for (int off = 32; off; off >>= 1) t += __shfl_xor(t, off);
            inner[p] = t;
        }
        if (l == 0) {
            double num = inner[0] * inner[1];
            double den = inner[2] * inner[3];
            if (fabs(den) < 1e-9) den = 1e-9;
            double crc = num / den;
            if (fabs(crc) < 1e-9) crc = 1e-9;
            double ratio = crin_sh / crc;
            scalef[0] = (float)pow(fabs(ratio), 0.25);
        }
    }
}

// ---------------- final GEMM: out = ((U/sumf) @ Wo.T + bo) * scalef ----------------
__global__ void __launch_bounds__(256, 2)
k_out2(const float* __restrict__ U, const float* __restrict__ Wo,
       const float* __restrict__ bo, const double* __restrict__ sumf,
       const float* __restrict__ scalef, float* __restrict__ out, int N) {
    __shared__ float4 xs4[64 * 32];   // 32 KB
    __shared__ float4 ws4[64 * 16];   // 16 KB (one K-half of Wo)
    int tid = threadIdx.x;
    int rg = tid >> 4;       // 16 row-groups x 4 rows
    int cg = tid & 15;       // 16 col-groups x 4 cols
    int base = blockIdx.x * 64;

    float si0 = (float)(1.0 / sumf[0]);
    float si1 = (float)(1.0 / sumf[1]);
    const float4* U4 = (const float4*)U;
    const float4* Wo4 = (const float4*)Wo;

#pragma unroll
    for (int i2 = 0; i2 < 8; i2++) {
        int idx = tid + i2 * 256;
        int r = idx >> 5, kc = idx & 31;
        int row = base + r;
        float4 v = {0.f, 0.f, 0.f, 0.f};
        if (row < N) {
            v = U4[(size_t)row * 32 + kc];
            float si = (kc < 16) ? si0 : si1;
            v.x *= si; v.y *= si; v.z *= si; v.w *= si;
        }
        xs4[XS2(r, kc)] = v;
    }

    float acc[4][4];
#pragma unroll
    for (int i = 0; i < 4; i++)
#pragma unroll
        for (int j = 0; j < 4; j++) acc[i][j] = 0.f;

    for (int kp = 0; kp < 2; kp++) {
        __syncthreads();
#pragma unroll
        for (int i2 = 0; i2 < 4; i2++) {
            int idx = tid + i2 * 256;
            int c = idx >> 4, kc2 = idx & 15;
            ws4[WS2(c, kc2)] = Wo4[(size_t)c * 32 + kp * 16 + kc2];
        }
        __syncthreads();
        for (int kc2 = 0; kc2 < 16; kc2++) {
            int kc = kp * 16 + kc2;
            float4 xa[4], wb[4];
#pragma unroll
            for (int i = 0; i < 4; i++) xa[i] = xs4[XS2(rg * 4 + i, kc)];
#pragma unroll
            for (int j = 0; j < 4; j++) wb[j] = ws4[WS2(cg * 4 + j, kc2)];
#pragma unroll
            for (int i = 0; i < 4; i++)
#pragma unroll
                for (int j = 0; j < 4; j++) {
                    acc[i][j] = fmaf(xa[i].x, wb[j].x, acc[i][j]);
                    acc[i][j] = fmaf(xa[i].y, wb[j].y, acc[i][j]);
                    acc[i][j] = fmaf(xa[i].z, wb[j].z, acc[i][j]);
                    acc[i][j] = fmaf(xa[i].w, wb[j].w, acc[i][j]);
                }
        }
    }

    float4 bb = ((const float4*)bo)[cg];
    float sf = scalef[0];
#pragma unroll
    for (int i = 0; i < 4; i++) {
        int row = base + rg * 4 + i;
        if (row < N) {
            float4 o;
            o.x = (acc[i][0] + bb.x) * sf;
            o.y = (acc[i][1] + bb.y) * sf;
            o.z = (acc[i][2] + bb.z) * sf;
            o.w = (acc[i][3] + bb.w) * sf;
            ((float4*)(out + (size_t)row * 64))[cg] = o;
        }
    }
}

extern "C" void kernel_launch(void* const* d_in, const int* in_sizes, int n_in,
                              void* d_out, int out_size, void* d_ws, size_t ws_size,
                              hipStream_t stream) {
    const float* x  = (const float*)d_in[0];
    const int*   ei = (const int*)d_in[1];
    const float* Wq = (const float*)d_in[2];
    const float* bq = (const float*)d_in[3];
    const float* Wk = (const float*)d_in[4];
    const float* bk = (const float*)d_in[5];
    const float* Wv = (const float*)d_in[6];
    const float* bv = (const float*)d_in[7];
    const float* Wo = (const float*)d_in[8];
    const float* bo = (const float*)d_in[9];
    float* out = (float*)d_out;

    const int N = in_sizes[0] / 128;   // 100000
    const int E = in_sizes[1] / 2;
    const size_t NR = (size_t)N * 128;
    const int NB64 = (N + 63) / 64;    // 1563 tiled-GEMM blocks
    const int HB = 512;                // histogram-role blocks appended to k_qkv3
    const int GB = (N + 7) / 8;        // 12500 edge-kernel blocks
    const int T = (N + 1023) / 1024;

    float* qn = (float*)d_ws;          // N*128 ; reused as U after k_edge
    float* kv = qn + NR;               // N*256 (k|v interleaved per node)
    int* counts = (int*)(kv + NR * 2);         // N
    int* offs   = counts + N;                  // N+2
    int* cursor = offs + N + 2;                // N
    int* ccol   = cursor + N;                  // E
    double* psum = (double*)(ccol + E);        // GB*2 partial expsums
    int* tsum   = (int*)(psum + (size_t)GB * 2);  // T scan tiles
    double* sumf = (double*)(tsum + T + (T & 1)); // 2 doubles (8B aligned)
    float* scalef = (float*)(sumf + 2);           // 1

    float* U = qn;  // aggregation output aliases q (per-n read-then-write)

    hipMemsetAsync(counts, 0, (size_t)N * sizeof(int), stream);
    k_qkv3<<<NB64 + HB, 128, 0, stream>>>(x, Wq, bq, Wk, bk, Wv, bv,
                                          qn, kv, ei, counts, NB64, N, E);
    k_scan1<<<T, 256, 0, stream>>>(counts, offs, tsum, N);
    k_scan2<<<1, 64, 0, stream>>>(tsum, offs, T, N);
    k_scan3<<<(N + 255) / 256, 256, 0, stream>>>(offs, cursor, tsum, N);
    k_fill<<<1024, 256, 0, stream>>>(ei, cursor, ccol, E);
    k_edge<<<GB, 256, 0, stream>>>(qn, kv, offs, ccol, U, psum, N);
    k_sum2<<<1, 256, 0, stream>>>(psum, sumf, GB);
    k_crout4<<<1, 256, 0, stream>>>(x, U, Wo, bo, sumf, scalef);
    k_out2<<<NB64, 256, 0, stream>>>(U, Wo, bo, sumf, scalef, out, N);
}